// Round 7
// baseline (397.110 us; speedup 1.0000x reference)
//
#include <hip/hip_runtime.h>

typedef unsigned short u16;
typedef float f32x4 __attribute__((ext_vector_type(4)));
typedef float f32x8 __attribute__((ext_vector_type(8)));
typedef u16   u16x4 __attribute__((ext_vector_type(4)));
typedef u16   u16x8 __attribute__((ext_vector_type(8)));
typedef __bf16 bf16x8 __attribute__((ext_vector_type(8)));

// ---------------- workspace layout (bytes) ----------------
#define WS_W       0u
#define WS_BIASRH  512u
#define WS_WPB     25600u
#define WS_PHWB    1074176u
#define WS_RW1B    2122752u
#define WS_W1B     2647040u
#define WS_W2B     21521408u
#define WS_XPB     40395776u
#define WS_H1B     52978688u
#define WS_OUTB    90727424u
#define WS_RHB     103310336u

#define OUT_LG   6291456
#define OUT_PRED 6451200
#define OUT_DEC  19034112

__device__ __forceinline__ u16 f2bf(float f) {
    unsigned u = __builtin_bit_cast(unsigned, f);
    return (u16)((u + 0x7FFFu + ((u >> 16) & 1u)) >> 16);
}
__device__ __forceinline__ float bf2f(u16 h) {
    return __builtin_bit_cast(float, (unsigned)h << 16);
}

typedef __attribute__((address_space(1))) void* gas1p;
typedef __attribute__((address_space(3))) void* las3p;
__device__ __forceinline__ void gload16(const u16* g, u16* l) {
    __builtin_amdgcn_global_load_lds((gas1p)(unsigned long long)g,
                                     (las3p)(unsigned)(unsigned long long)l,
                                     16, 0, 0);
}

__device__ __forceinline__ void zero_acc(f32x4 (&a)[4][4]) {
#pragma unroll
    for (int i = 0; i < 4; i++)
#pragma unroll
        for (int j = 0; j < 4; j++)
            a[i][j] = (f32x4){0.f, 0.f, 0.f, 0.f};
}

// 128x128 tile, BK=32, 4 waves (2x2 of 64x64). C = A * B^T.
// Double-buffered LDS, counted-vmcnt pipeline (1 tile in flight).
// VERIFIED structure (R3 bench, 394.48us) — do not perturb scheduling.
__device__ __forceinline__ void mfma_loop(
    const u16* __restrict__ Ab, size_t pa,
    const u16* __restrict__ Bb, size_t pb,
    int K, u16* sA, u16* sB, f32x4 (&acc)[4][4])
{
    const int tid = threadIdx.x;
    const int l = tid & 63, wv = tid >> 6;
    const int wm = (wv >> 1) * 64, wn = (wv & 1) * 64;
    const int m16 = l & 15, k8 = l >> 4;
    const int kc = (tid & 3) * 8;
    const size_t ra0 = (size_t)(tid >> 2) * pa + kc;
    const size_t ra1 = ra0 + 64 * pa;
    const size_t rb0 = (size_t)(tid >> 2) * pb + kc;
    const size_t rb1 = rb0 + 64 * pb;
    const int aO = (wm + m16) * 32 + k8 * 8;
    const int bO = (wn + m16) * 32 + k8 * 8;
    gload16(Ab + ra0, sA + tid * 8);
    gload16(Ab + ra1, sA + (tid + 256) * 8);
    gload16(Bb + rb0, sB + tid * 8);
    gload16(Bb + rb1, sB + (tid + 256) * 8);
    int cur = 0;
    for (int kt = 0; kt < K; kt += 32) {
        __builtin_amdgcn_s_barrier();            // b1: all done reading buf[nx]
        const int nx = cur ^ 1;
        if (kt + 32 < K) {
            const int kn = kt + 32;
            gload16(Ab + ra0 + kn, sA + nx * 4096 + tid * 8);
            gload16(Ab + ra1 + kn, sA + nx * 4096 + (tid + 256) * 8);
            gload16(Bb + rb0 + kn, sB + nx * 4096 + tid * 8);
            gload16(Bb + rb1 + kn, sB + nx * 4096 + (tid + 256) * 8);
            asm volatile("s_waitcnt vmcnt(4)" ::: "memory");   // tile-kt landed; next 4 in flight
        } else {
            asm volatile("s_waitcnt vmcnt(0)" ::: "memory");
        }
        __builtin_amdgcn_s_barrier();            // b2: every wave's tile-kt loads landed
        const u16* cA = sA + cur * 4096;
        const u16* cB = sB + cur * 4096;
        bf16x8 af[4], bv[4];
#pragma unroll
        for (int i = 0; i < 4; i++) af[i] = *(const bf16x8*)(cA + aO + i * 512);
#pragma unroll
        for (int i = 0; i < 4; i++) bv[i] = *(const bf16x8*)(cB + bO + i * 512);
#pragma unroll
        for (int i = 0; i < 4; i++)
#pragma unroll
            for (int j = 0; j < 4; j++)
                acc[i][j] = __builtin_amdgcn_mfma_f32_16x16x32_bf16(af[i], bv[j], acc[i][j], 0, 0, 0);
        cur = nx;
    }
}

// 64x128 tile, BK=32, 4 waves side-by-side in N. Same pipelined scheme.
__device__ __forceinline__ void mfma_loop64(
    const u16* __restrict__ Ab, size_t pa,
    const u16* __restrict__ Bb, size_t pb,
    int K, u16* sA, u16* sB, f32x4 (&acc)[4][2])
{
    const int tid = threadIdx.x;
    const int l = tid & 63, wv = tid >> 6;
    const int m16 = l & 15, k8 = l >> 4;
    const int kc = (tid & 3) * 8;
    const size_t ra0 = (size_t)(tid >> 2) * pa + kc;
    const size_t rb0 = (size_t)(tid >> 2) * pb + kc;
    const size_t rb1 = rb0 + 64 * pb;
    const int aO = m16 * 32 + k8 * 8;
    const int bO = (wv * 32 + m16) * 32 + k8 * 8;
    gload16(Ab + ra0, sA + tid * 8);
    gload16(Bb + rb0, sB + tid * 8);
    gload16(Bb + rb1, sB + (tid + 256) * 8);
    int cur = 0;
    for (int kt = 0; kt < K; kt += 32) {
        __builtin_amdgcn_s_barrier();
        const int nx = cur ^ 1;
        if (kt + 32 < K) {
            const int kn = kt + 32;
            gload16(Ab + ra0 + kn, sA + nx * 2048 + tid * 8);
            gload16(Bb + rb0 + kn, sB + nx * 4096 + tid * 8);
            gload16(Bb + rb1 + kn, sB + nx * 4096 + (tid + 256) * 8);
            asm volatile("s_waitcnt vmcnt(3)" ::: "memory");
        } else {
            asm volatile("s_waitcnt vmcnt(0)" ::: "memory");
        }
        __builtin_amdgcn_s_barrier();
        const u16* cA = sA + cur * 2048;
        const u16* cB = sB + cur * 4096;
        bf16x8 af[4], bv[2];
#pragma unroll
        for (int i = 0; i < 4; i++) af[i] = *(const bf16x8*)(cA + aO + i * 512);
#pragma unroll
        for (int j = 0; j < 2; j++) bv[j] = *(const bf16x8*)(cB + bO + j * 512);
#pragma unroll
        for (int i = 0; i < 4; i++)
#pragma unroll
            for (int j = 0; j < 2; j++)
                acc[i][j] = __builtin_amdgcn_mfma_f32_16x16x32_bf16(af[i], bv[j], acc[i][j], 0, 0, 0);
        cur = nx;
    }
}

// ---------------- conversion + softmax(w) ----------------
__global__ __launch_bounds__(256) void cvt6(
    const float* __restrict__ opW1, u16* __restrict__ w1b,
    const float* __restrict__ opW2, u16* __restrict__ w2b,
    const float* __restrict__ Wp,   u16* __restrict__ wpb,
    const float* __restrict__ phW,  u16* __restrict__ phwb,
    const float* __restrict__ rW1,  u16* __restrict__ rw1b,
    const float* __restrict__ op_logits, float* __restrict__ wbuf)
{
    if (blockIdx.x == 0 && threadIdx.x < 12) {
        const int t = threadIdx.x;
        float l0 = op_logits[t*3+0], l1 = op_logits[t*3+1], l2 = op_logits[t*3+2];
        float mx = fmaxf(l0, fmaxf(l1, l2));
        float e0 = expf(l0-mx), e1 = expf(l1-mx), e2 = expf(l2-mx);
        float inv = 1.f / (e0 + e1 + e2);
        wbuf[t*3+0] = e0*inv; wbuf[t*3+1] = e1*inv; wbuf[t*3+2] = e2*inv;
    }
    int i = (blockIdx.x * 256 + threadIdx.x) * 4;
    const float* s; u16* d;
    if (i < 9437184)                    { s = opW1; d = w1b; }
    else if ((i -= 9437184) < 9437184)  { s = opW2; d = w2b; }
    else if ((i -= 9437184) < 524288)   { s = Wp;   d = wpb; }
    else if ((i -= 524288)  < 524288)   { s = phW;  d = phwb; }
    else {
        i -= 524288;  // [0, 262144): rW1 cols 0..511 of 519
        int row = i >> 9, j = i & 511;
        const float* sr = rW1 + (size_t)row * 519 + j;
        u16x4 o = { f2bf(sr[0]), f2bf(sr[1]), f2bf(sr[2]), f2bf(sr[3]) };
        *(u16x4*)(rw1b + i) = o;
        return;
    }
    f32x4 v = *(const f32x4*)(s + i);
    u16x4 o = { f2bf(v[0]), f2bf(v[1]), f2bf(v[2]), f2bf(v[3]) };
    *(u16x4*)(d + i) = o;
}

// ---------------- G1: xp = x @ Wp^T + bp -> bf16 ----------------
// 64x128 tiles; 1D grid 768 with XCD swizzle. 2-deep A-register prefetch.
#define XP_STEP(KT, REG, CUR) do {                                              \
    __builtin_amdgcn_s_barrier();                                               \
    gload16(Bb + rb0 + (KT) + 32, sB + (1-(CUR)) * 4096 + tid * 8);             \
    gload16(Bb + rb1 + (KT) + 32, sB + (1-(CUR)) * 4096 + (tid + 256) * 8);     \
    { u16x8 c_;                                                                 \
      _Pragma("unroll") for (int j_ = 0; j_ < 8; j_++) c_[j_] = f2bf(REG[j_]);  \
      *(u16x8*)(sA + (1-(CUR)) * 2048 + tid * 8) = c_; }                        \
    REG = *(const f32x8*)(xrow + (((KT) + 96) & 1023));                         \
    asm volatile("s_waitcnt lgkmcnt(0)" ::: "memory");                          \
    asm volatile("s_waitcnt vmcnt(4)" ::: "memory");                            \
    __builtin_amdgcn_s_barrier();                                               \
    { const u16* cA_ = sA + (CUR) * 2048; const u16* cB_ = sB + (CUR) * 4096;   \
      bf16x8 af_[4], bv_[2];                                                    \
      _Pragma("unroll") for (int i_ = 0; i_ < 4; i_++)                          \
          af_[i_] = *(const bf16x8*)(cA_ + aO + i_ * 512);                      \
      _Pragma("unroll") for (int j_ = 0; j_ < 2; j_++)                          \
          bv_[j_] = *(const bf16x8*)(cB_ + bO + j_ * 512);                      \
      _Pragma("unroll") for (int i_ = 0; i_ < 4; i_++)                          \
      _Pragma("unroll") for (int j_ = 0; j_ < 2; j_++)                          \
          acc[i_][j_] = __builtin_amdgcn_mfma_f32_16x16x32_bf16(                \
              af_[i_], bv_[j_], acc[i_][j_], 0, 0, 0); }                        \
} while (0)

__global__ __launch_bounds__(256) void kgemm_xp(
    const float* __restrict__ x, const u16* __restrict__ wpb,
    const float* __restrict__ bp, u16* __restrict__ xpb)
{
    __shared__ u16 sA[4096], sB[8192];           // 2x2048 / 2x4096
    const int id = blockIdx.x;                   // 768 blocks
    const int cb = (id >> 3) & 3;                // col block 0..3
    const int yb = (id & 7) + ((id >> 5) << 3);  // row block 0..191
    const int rowBase = yb * 64, colBase = cb * 128;
    const int tid = threadIdx.x, l = tid & 63, wv = tid >> 6;
    const int m16 = l & 15, k8 = l >> 4;
    const int kc = (tid & 3) * 8;
    const float* xrow = x + (size_t)(rowBase + (tid >> 2)) * 1024 + kc;
    const u16* Bb = wpb + (size_t)colBase * 1024;
    const size_t rb0 = (size_t)(tid >> 2) * 1024 + kc;
    const size_t rb1 = rb0 + 64 * 1024;
    const int aO = m16 * 32 + k8 * 8;
    const int bO = (wv * 32 + m16) * 32 + k8 * 8;
    f32x4 acc[4][2];
#pragma unroll
    for (int i = 0; i < 4; i++)
#pragma unroll
        for (int j = 0; j < 2; j++) acc[i][j] = (f32x4){0.f,0.f,0.f,0.f};

    // prologue: tile0 -> buf0; A(1),A(2) left in flight in rEv/rOd
    gload16(Bb + rb0, sB + tid * 8);
    gload16(Bb + rb1, sB + (tid + 256) * 8);
    {
        f32x8 a0 = *(const f32x8*)(xrow);        // auto-wait drains B(0) too (once)
        u16x8 c;
#pragma unroll
        for (int j = 0; j < 8; j++) c[j] = f2bf(a0[j]);
        *(u16x8*)(sA + tid * 8) = c;
    }
    f32x8 rEv = *(const f32x8*)(xrow + 32);      // A(1), consumed at t=0
    f32x8 rOd = *(const f32x8*)(xrow + 64);      // A(2), consumed at t=1
    asm volatile("s_waitcnt lgkmcnt(0)" ::: "memory");

    for (int kt = 0; kt < 960; kt += 64) {       // t = 0..29 (pairs)
        XP_STEP(kt, rEv, 0);
        XP_STEP(kt + 32, rOd, 1);
    }
    XP_STEP(960, rEv, 0);                        // t = 30
    // t = 31 (cur = 1): nothing left to stage
    __builtin_amdgcn_s_barrier();
    asm volatile("s_waitcnt vmcnt(0) lgkmcnt(0)" ::: "memory");
    __builtin_amdgcn_s_barrier();
    {
        const u16* cA = sA + 2048;
        const u16* cB = sB + 4096;
        bf16x8 af[4], bv[2];
#pragma unroll
        for (int i = 0; i < 4; i++) af[i] = *(const bf16x8*)(cA + aO + i * 512);
#pragma unroll
        for (int j = 0; j < 2; j++) bv[j] = *(const bf16x8*)(cB + bO + j * 512);
#pragma unroll
        for (int i = 0; i < 4; i++)
#pragma unroll
            for (int j = 0; j < 2; j++)
                acc[i][j] = __builtin_amdgcn_mfma_f32_16x16x32_bf16(af[i], bv[j], acc[i][j], 0, 0, 0);
    }
#pragma unroll
    for (int in = 0; in < 2; in++) {
        const int gc = colBase + wv * 32 + in * 16 + m16;
        const float bv = bp[gc];
#pragma unroll
        for (int im = 0; im < 4; im++) {
            const int gr = rowBase + im * 16 + k8 * 4;
#pragma unroll
            for (int r = 0; r < 4; r++)
                xpb[(size_t)(gr + r) * 512 + gc] = f2bf(acc[im][in][r] + bv);
        }
    }
}

// ---------------- G2: h1[t,k] = relu(xg @ W1^T + b1) -> bf16 ----------------
__global__ __launch_bounds__(256) void kgemm_h1(
    const u16* __restrict__ xpb, const u16* __restrict__ w1b,
    const float* __restrict__ opb1, u16* __restrict__ h1b)
{
    __shared__ u16 sA[8192], sB[8192];
    const int id = blockIdx.x;
    const int seg = id >> 5, i = id & 31, t = seg / 3;
    const int xb = i & 3;                        // = xcd & 3 -> B col-tile per XCD
    const int yb = (i >> 3) + ((i >> 2) & 1) * 4;
    const int rowBase = yb * 128, colBase = xb * 128;
    f32x4 acc[4][4]; zero_acc(acc);
    // A row gi -> memory row gi*12 + t  (pitch 12*512)
    mfma_loop(xpb + (size_t)rowBase * 6144 + (size_t)t * 512, 6144,
              w1b + (size_t)seg * 262144 + (size_t)colBase * 512, 512, 512, sA, sB, acc);
    const int tid = threadIdx.x, l = tid & 63, wv = tid >> 6;
    const int wm = (wv >> 1) * 64, wn = (wv & 1) * 64, m16 = l & 15, k8 = l >> 4;
    u16* hseg = h1b + (size_t)seg * 524288;
#pragma unroll
    for (int in = 0; in < 4; in++) {
        const int gc = colBase + wn + in * 16 + m16;
        const float bv = opb1[seg * 512 + gc];
#pragma unroll
        for (int im = 0; im < 4; im++) {
            const int gr = rowBase + wm + im * 16 + k8 * 4;
#pragma unroll
            for (int r = 0; r < 4; r++)
                hseg[(size_t)(gr + r) * 512 + gc] = f2bf(fmaxf(acc[im][in][r] + bv, 0.f));
        }
    }
}

// ------- G3: out[t] = sum_k w[t,k]*relu(h1 @ W2^T + b2) -> f32 + bf16 -------
__global__ __launch_bounds__(256) void kgemm_out(
    const u16* __restrict__ h1b, const u16* __restrict__ w2b,
    const float* __restrict__ opb2, const float* __restrict__ wbuf,
    float* __restrict__ outF, u16* __restrict__ outb)
{
    __shared__ u16 sA[4096], sB[8192];
    const int id = blockIdx.x;
    const int t = id >> 6, i = id & 63;
    const int a = i & 1, b2i = (i >> 1) & 3, q = i >> 3;
    const int xb = 2 * a + (q & 1), yb = 4 * b2i + (q >> 1);
    const int rowBase = yb * 64, colBase = xb * 128;
    const int tid = threadIdx.x, l = tid & 63, wv = tid >> 6;
    const int m16 = l & 15, k8 = l >> 4;
    float oac[4][2][4];
#pragma unroll
    for (int i1 = 0; i1 < 4; i1++)
#pragma unroll
        for (int j = 0; j < 2; j++)
#pragma unroll
            for (int r = 0; r < 4; r++) oac[i1][j][r] = 0.f;

    for (int kk = 0; kk < 3; kk++) {
        const int seg = t * 3 + kk;
        f32x4 acc[4][2];
#pragma unroll
        for (int i1 = 0; i1 < 4; i1++)
#pragma unroll
            for (int j = 0; j < 2; j++) acc[i1][j] = (f32x4){0.f,0.f,0.f,0.f};
        mfma_loop64(h1b + ((size_t)seg * 1024 + rowBase) * 512, 512,
                    w2b + (size_t)seg * 262144 + (size_t)colBase * 512, 512, 512, sA, sB, acc);
        const float wk = wbuf[seg];
#pragma unroll
        for (int in = 0; in < 2; in++) {
            const float bv = opb2[seg * 512 + colBase + wv * 32 + in * 16 + m16];
#pragma unroll
            for (int im = 0; im < 4; im++)
#pragma unroll
                for (int r = 0; r < 4; r++)
                    oac[im][in][r] += wk * fmaxf(acc[im][in][r] + bv, 0.f);
        }
    }
#pragma unroll
    for (int im = 0; im < 4; im++)
#pragma unroll
        for (int r = 0; r < 4; r++) {
            const int gi = rowBase + im * 16 + k8 * 4 + r;
            const size_t b = (size_t)gi * 12 + t;   // scatter back to patch order
#pragma unroll
            for (int in = 0; in < 2; in++) {
                const int gc = colBase + wv * 32 + in * 16 + m16;
                const float v = oac[im][in][r];
                outF[b * 512 + gc] = v;
                outb[b * 512 + gc] = f2bf(v);
            }
        }
}

// ------- G4+G5 fused: pred = out @ phW^T + phb  |  rh = relu(out @ rW1^T + bias_rh) -------
__global__ __launch_bounds__(256) void kgemm_predrh(
    const u16* __restrict__ outb, const u16* __restrict__ phwb,
    const float* __restrict__ phb, const u16* __restrict__ rw1b,
    const float* __restrict__ bias_rh, float* __restrict__ outPred,
    u16* __restrict__ rhb)
{
    __shared__ u16 sA[8192], sB[8192];
    const int id = blockIdx.x;
    const int j = id >> 3;
    const int bz = j % 12;                        // 0..7 pred colblocks, 8..11 rh
    const int yb = (id & 7) + (j / 12) * 8;       // 0..95
    const int rowBase = yb * 128;
    const bool isPred = bz < 8;
    const int colBase = (isPred ? bz : bz - 8) * 128;
    const u16* Bb = isPred ? (phwb + (size_t)colBase * 512)
                           : (rw1b + (size_t)colBase * 512);
    f32x4 acc[4][4]; zero_acc(acc);
    mfma_loop(outb + (size_t)rowBase * 512, 512, Bb, 512, 512, sA, sB, acc);
    const int tid = threadIdx.x, l = tid & 63, wv = tid >> 6;
    const int wm = (wv >> 1) * 64, wn = (wv & 1) * 64, m16 = l & 15, k8 = l >> 4;
    if (isPred) {
#pragma unroll
        for (int in = 0; in < 4; in++) {
            const int gc = colBase + wn + in * 16 + m16;
            const float bv = phb[gc];
#pragma unroll
            for (int im = 0; im < 4; im++) {
                const int gr = rowBase + wm + im * 16 + k8 * 4;
#pragma unroll
                for (int r = 0; r < 4; r++)
                    outPred[(size_t)(gr + r) * 1024 + gc] = acc[im][in][r] + bv;
            }
        }
    } else {
#pragma unroll
        for (int in = 0; in < 4; in++) {
            const int gc = colBase + wn + in * 16 + m16;
#pragma unroll
            for (int im = 0; im < 4; im++) {
                const int gr = rowBase + wm + im * 16 + k8 * 4;
#pragma unroll
                for (int r = 0; r < 4; r++) {
                    const int b = gr + r;
                    const float bv = bias_rh[(b % 12) * 512 + gc];
                    rhb[(size_t)b * 512 + gc] = f2bf(fmaxf(acc[im][in][r] + bv, 0.f));
                }
            }
        }
    }
}

// ---------------- per-group streaming reductions -> per-wave partials ----------------
// quarter-split: 4096 waves, each handles 3 of the 12 t-rows of one group.
__global__ __launch_bounds__(256) void rowred(
    const float* __restrict__ outF, const u16* __restrict__ xpb,
    const float* __restrict__ noise, float* __restrict__ partials)
{
    const int tid = threadIdx.x, l = tid & 63, wv = tid >> 6;
    const int gw = blockIdx.x * 4 + wv;          // 0..4095
    const int g = gw >> 2, q = gw & 3;
    const size_t base = (size_t)g * 12 * 512 + l * 8;
    float* pout = partials + (size_t)g * 60 + q * 15;
#pragma unroll
    for (int t0 = 0; t0 < 3; t0++) {
        const int t = q * 3 + t0;
        const size_t off = base + (size_t)t * 512;
        f32x8 ov = *(const f32x8*)(outF + off);
        f32x8 nv = *(const f32x8*)(noise + off);
        u16x8 xv = *(const u16x8*)(xpb + off);
        float s1 = 0, s2 = 0, s3 = 0, s4 = 0;
#pragma unroll
        for (int j = 0; j < 8; j++) {
            float xg = bf2f(xv[j]);
            float o = ov[j];
            float d = o - xg;
            s1 += d * d; s2 += xg * xg; s3 += fabsf(o); s4 += nv[j] * nv[j];
        }
#pragma unroll
        for (int off2 = 32; off2 > 0; off2 >>= 1) {
            s1 += __shfl_xor(s1, off2);
            s2 += __shfl_xor(s2, off2);
            s3 += __shfl_xor(s3, off2);
            s4 += __shfl_xor(s4, off2);
        }
        if (l < 5) {
            float v = (l == 0) ? s1 : (l == 1) ? s2 : (l == 2) ? s3
                    : (l == 3) ? s4 : s1 * s1;
            pout[t0 * 5 + l] = v;
        }
    }
}

// ---------------- partial-reduce + signals -> decision + folded routing bias ----------------
__global__ __launch_bounds__(256) void sig_kernel(
    const float* __restrict__ op_logits, const float* __restrict__ id_emb,
    const float* __restrict__ rW1, const float* __restrict__ rb1,
    const float* __restrict__ gW1, const float* __restrict__ gb1,
    const float* __restrict__ gW2, const float* __restrict__ gb2,
    const float* __restrict__ partials, float* __restrict__ bias_rh,
    float* __restrict__ outDec)
{
    const int t = blockIdx.x, tid = threadIdx.x;
    __shared__ float sig[7], ex7[7], gch[512], red[256], accv[5];
    float a[5] = {0.f, 0.f, 0.f, 0.f, 0.f};
    for (int g = tid; g < 1024; g += 256) {
        const float* p = partials + (size_t)g * 60 + t * 5;
#pragma unroll
        for (int s = 0; s < 5; s++) a[s] += p[s];
    }
#pragma unroll
    for (int s = 0; s < 5; s++) {
        red[tid] = a[s]; __syncthreads();
        for (int k = 128; k > 0; k >>= 1) { if (tid < k) red[tid] += red[tid + k]; __syncthreads(); }
        if (tid == 0) accv[s] = red[0];
        __syncthreads();
    }
    if (tid == 0) {
        float l0 = op_logits[t*3+0], l1 = op_logits[t*3+1], l2 = op_logits[t*3+2];
        float mx = fmaxf(l0, fmaxf(l1, l2));
        float e0 = expf(l0-mx), e1 = expf(l1-mx), e2 = expf(l2-mx);
        float es = e0 + e1 + e2;
        float w0 = e0/es, w1 = e1/es, w2 = e2/es;
        float mean = (w0 + w1 + w2) * (1.f/3.f);
        float var = ((w0-mean)*(w0-mean) + (w1-mean)*(w1-mean) + (w2-mean)*(w2-mean)) * 0.5f;
        float conflict = sqrtf(var);
        float inv_s = 1.f / (w0 + w1 + w2 + 1e-6f);
        float u0 = w0*inv_s, u1 = w1*inv_s, u2 = w2*inv_s;
        float ent = -(u0*logf(fmaxf(u0,1e-6f)) + u1*logf(fmaxf(u1,1e-6f)) + u2*logf(fmaxf(u2,1e-6f)));
        const float inv = 1.f / (1024.f * 512.f);
        float plast = accv[0] * inv;                 // pred_err mean == last_plasticity
        float nov   = accv[1] * inv;
        float spars = accv[2] * inv;
        float plasticity = 1e-4f * accv[3] * inv;
        float pe2 = accv[4] * (1.f / (1024.f * 512.f * 512.f));
        float na = 0.01f * plast;
        float rvar = pe2 - 2.f*na*plast + na*na;
        sig[0]=plasticity; sig[1]=nov; sig[2]=plast; sig[3]=ent; sig[4]=spars; sig[5]=-plast; sig[6]=rvar;
        ex7[0]=id_emb[t*4+0]; ex7[1]=id_emb[t*4+1]; ex7[2]=id_emb[t*4+2]; ex7[3]=id_emb[t*4+3];
        ex7[4]=nov; ex7[5]=conflict; ex7[6]=plast;
    }
    __syncthreads();
    for (int h = tid; h < 512; h += 256) {
        float aa = gb1[t*512 + h];
#pragma unroll
        for (int j = 0; j < 7; j++) aa += gW1[(t*512 + h)*7 + j] * sig[j];
        gch[h] = fmaxf(aa, 0.f);
        float bb = rb1[h];
#pragma unroll
        for (int e = 0; e < 7; e++) bb += ex7[e] * rW1[(size_t)h * 519 + 512 + e];
        bias_rh[t*512 + h] = bb;
    }
    __syncthreads();
    float p0 = 0.f, p1 = 0.f;
    for (int h = tid; h < 512; h += 256) {
        p0 += gW2[(t*2 + 0)*512 + h] * gch[h];
        p1 += gW2[(t*2 + 1)*512 + h] * gch[h];
    }
    red[tid] = p0; __syncthreads();
    for (int s = 128; s > 0; s >>= 1) { if (tid < s) red[tid] += red[tid + s]; __syncthreads(); }
    if (tid == 0) outDec[t*2 + 0] = red[0] + gb2[t*2 + 0];
    __syncthreads();
    red[tid] = p1; __syncthreads();
    for (int s = 128; s > 0; s >>= 1) { if (tid < s) red[tid] += red[tid + s]; __syncthreads(); }
    if (tid == 0) outDec[t*2 + 1] = red[0] + gb2[t*2 + 1];
}

// ---------------- logits = rh @ rW2^T + rb2 (one wave per row) ----------------
__global__ __launch_bounds__(256) void logits_kernel(
    const u16* __restrict__ rhb, const float* __restrict__ rW2,
    const float* __restrict__ rb2, float* __restrict__ outLg)
{
    __shared__ float T2[512 * 13];
    __shared__ float rb2s[16];
    const int tid = threadIdx.x;
    for (int i = tid; i < 6656; i += 256) {
        int o = i >> 9, j = i & 511;
        T2[j * 13 + o] = rW2[i];    // transposed+13-pitch: conflict-free reads
    }
    if (tid < 13) rb2s[tid] = rb2[tid];
    __syncthreads();
    const int l = tid & 63, wv = tid >> 6;
    const size_t b = (size_t)blockIdx.x * 4 + wv;
    const u16* rrow = rhb + b * 512;
    float rv[8];
#pragma unroll
    for (int jj = 0; jj < 8; jj++) rv[jj] = bf2f(rrow[l + 64 * jj]);
    float p[13];
#pragma unroll
    for (int o = 0; o < 13; o++) p[o] = 0.f;
#pragma unroll
    for (int jj = 0; jj < 8; jj++) {
        const float* tp = T2 + (l + 64 * jj) * 13;
#pragma unroll
        for (int o = 0; o < 13; o++) p[o] += rv[jj] * tp[o];
    }
#pragma unroll
    for (int o = 0; o < 13; o++) {
#pragma unroll
        for (int off = 32; off > 0; off >>= 1) p[o] += __shfl_xor(p[o], off);
    }
    if (l == 0) {
        float* orow = outLg + b * 13;
#pragma unroll
        for (int o = 0; o < 13; o++) orow[o] = p[o] + rb2s[o];
    }
}

extern "C" void kernel_launch(void* const* d_in, const int* in_sizes, int n_in,
                              void* d_out, int out_size, void* d_ws, size_t ws_size,
                              hipStream_t stream)
{
    const float* x         = (const float*)d_in[0];
    const float* Wp        = (const float*)d_in[1];
    const float* bp        = (const float*)d_in[2];
    const float* opW1      = (const float*)d_in[3];
    const float* opb1      = (const float*)d_in[4];
    const float* opW2      = (const float*)d_in[5];
    const float* opb2      = (const float*)d_in[6];
    const float* op_logits = (const float*)d_in[7];
    const float* id_emb    = (const float*)d_in[8];
    const float* rW1       = (const float*)d_in[9];
    const float* rb1       = (const float*)d_in[10];
    const float* rW2       = (const float*)d_in[11];
    const float* rb2       = (const float*)d_in[12];
    const float* gW1       = (const float*)d_in[13];
    const float* gb1       = (const float*)d_in[14];
    const float* gW2       = (const float*)d_in[15];
    const float* gb2       = (const float*)d_in[16];
    const float* phW       = (const float*)d_in[17];
    const float* phb       = (const float*)d_in[18];
    const float* noise     = (const float*)d_in[19];

    char* ws = (char*)d_ws;
    float* wbuf    = (float*)(ws + WS_W);
    float* bias_rh = (float*)(ws + WS_BIASRH);
    u16* wpb  = (u16*)(ws + WS_WPB);
    u16* phwb = (u16*)(ws + WS_PHWB);
    u16* rw1b = (u16*)(ws + WS_RW1B);
    u16* w1b  = (u16*)(ws + WS_W1B);
    u16* w2b  = (u16*)(ws + WS_W2B);
    u16* xpb  = (u16*)(ws + WS_XPB);
    u16* h1b  = (u16*)(ws + WS_H1B);
    u16* outb = (u16*)(ws + WS_OUTB);
    u16* rhb  = (u16*)(ws + WS_RHB);
    float* partials = (float*)(ws + WS_W1B);   // aliases w1b, dead after kgemm_h1

    float* outF    = (float*)d_out;
    float* outLg   = outF + OUT_LG;
    float* outPred = outF + OUT_PRED;
    float* outDec  = outF + OUT_DEC;

    cvt6<<<19712, 256, 0, stream>>>(opW1, w1b, opW2, w2b, Wp, wpb,
                                    phW, phwb, rW1, rw1b, op_logits, wbuf);
    kgemm_xp  <<<768,  256, 0, stream>>>(x, wpb, bp, xpb);
    kgemm_h1  <<<1152, 256, 0, stream>>>(xpb, w1b, opb1, h1b);
    kgemm_out <<<768,  256, 0, stream>>>(h1b, w2b, opb2, wbuf, outF, outb);
    rowred    <<<1024, 256, 0, stream>>>(outF, xpb, noise, partials);
    sig_kernel<<<12,   256, 0, stream>>>(op_logits, id_emb, rW1, rb1, gW1, gb1,
                                         gW2, gb2, partials, bias_rh, outDec);
    kgemm_predrh<<<1152, 256, 0, stream>>>(outb, phwb, phb, rw1b, bias_rh,
                                           outPred, rhb);
    logits_kernel<<<3072, 256, 0, stream>>>(rhb, rW2, rb2, outLg);
}

// Round 8
// 379.786 us; speedup vs baseline: 1.0456x; 1.0456x over previous
//
#include <hip/hip_runtime.h>

typedef unsigned short u16;
typedef float f32x4 __attribute__((ext_vector_type(4)));
typedef float f32x8 __attribute__((ext_vector_type(8)));
typedef u16   u16x4 __attribute__((ext_vector_type(4)));
typedef u16   u16x8 __attribute__((ext_vector_type(8)));
typedef __bf16 bf16x8 __attribute__((ext_vector_type(8)));

// ---------------- workspace layout (bytes) ----------------
#define WS_W       0u
#define WS_BIASRH  512u
#define WS_WPB     25600u
#define WS_PHWB    1074176u
#define WS_RW1B    2122752u
#define WS_W1B     2647040u
#define WS_W2B     21521408u
#define WS_XPB     40395776u
#define WS_H1B     52978688u
#define WS_OUTB    90727424u
#define WS_RHB     103310336u

#define OUT_LG   6291456
#define OUT_PRED 6451200
#define OUT_DEC  19034112

__device__ __forceinline__ u16 f2bf(float f) {
    unsigned u = __builtin_bit_cast(unsigned, f);
    return (u16)((u + 0x7FFFu + ((u >> 16) & 1u)) >> 16);
}
__device__ __forceinline__ float bf2f(u16 h) {
    return __builtin_bit_cast(float, (unsigned)h << 16);
}

typedef __attribute__((address_space(1))) void* gas1p;
typedef __attribute__((address_space(3))) void* las3p;
__device__ __forceinline__ void gload16(const u16* g, u16* l) {
    __builtin_amdgcn_global_load_lds((gas1p)(unsigned long long)g,
                                     (las3p)(unsigned)(unsigned long long)l,
                                     16, 0, 0);
}

__device__ __forceinline__ void zero_acc(f32x4 (&a)[4][4]) {
#pragma unroll
    for (int i = 0; i < 4; i++)
#pragma unroll
        for (int j = 0; j < 4; j++)
            a[i][j] = (f32x4){0.f, 0.f, 0.f, 0.f};
}

// 128x128 tile, BK=32, 4 waves (2x2 of 64x64). C = A * B^T.
// Double-buffered LDS, counted-vmcnt pipeline (1 tile in flight).
// VERIFIED structure (R3/R6 bench) — do not perturb scheduling.
__device__ __forceinline__ void mfma_loop(
    const u16* __restrict__ Ab, size_t pa,
    const u16* __restrict__ Bb, size_t pb,
    int K, u16* sA, u16* sB, f32x4 (&acc)[4][4])
{
    const int tid = threadIdx.x;
    const int l = tid & 63, wv = tid >> 6;
    const int wm = (wv >> 1) * 64, wn = (wv & 1) * 64;
    const int m16 = l & 15, k8 = l >> 4;
    const int kc = (tid & 3) * 8;
    const size_t ra0 = (size_t)(tid >> 2) * pa + kc;
    const size_t ra1 = ra0 + 64 * pa;
    const size_t rb0 = (size_t)(tid >> 2) * pb + kc;
    const size_t rb1 = rb0 + 64 * pb;
    const int aO = (wm + m16) * 32 + k8 * 8;
    const int bO = (wn + m16) * 32 + k8 * 8;
    gload16(Ab + ra0, sA + tid * 8);
    gload16(Ab + ra1, sA + (tid + 256) * 8);
    gload16(Bb + rb0, sB + tid * 8);
    gload16(Bb + rb1, sB + (tid + 256) * 8);
    int cur = 0;
    for (int kt = 0; kt < K; kt += 32) {
        __builtin_amdgcn_s_barrier();            // b1: all done reading buf[nx]
        const int nx = cur ^ 1;
        if (kt + 32 < K) {
            const int kn = kt + 32;
            gload16(Ab + ra0 + kn, sA + nx * 4096 + tid * 8);
            gload16(Ab + ra1 + kn, sA + nx * 4096 + (tid + 256) * 8);
            gload16(Bb + rb0 + kn, sB + nx * 4096 + tid * 8);
            gload16(Bb + rb1 + kn, sB + nx * 4096 + (tid + 256) * 8);
            asm volatile("s_waitcnt vmcnt(4)" ::: "memory");   // tile-kt landed; next 4 in flight
        } else {
            asm volatile("s_waitcnt vmcnt(0)" ::: "memory");
        }
        __builtin_amdgcn_s_barrier();            // b2: every wave's tile-kt loads landed
        const u16* cA = sA + cur * 4096;
        const u16* cB = sB + cur * 4096;
        bf16x8 af[4], bv[4];
#pragma unroll
        for (int i = 0; i < 4; i++) af[i] = *(const bf16x8*)(cA + aO + i * 512);
#pragma unroll
        for (int i = 0; i < 4; i++) bv[i] = *(const bf16x8*)(cB + bO + i * 512);
#pragma unroll
        for (int i = 0; i < 4; i++)
#pragma unroll
            for (int j = 0; j < 4; j++)
                acc[i][j] = __builtin_amdgcn_mfma_f32_16x16x32_bf16(af[i], bv[j], acc[i][j], 0, 0, 0);
        cur = nx;
    }
}

// 64x128 tile, BK=64, 4 waves side-by-side in N. Same verified sync pattern
// (b1 -> stage nx -> counted vmcnt -> b2 -> compute cur), counts doubled:
// 6 loads/stage, vmcnt(6). K-subtile stored as two adjacent [.][32] halves so
// fragment addressing and K-order match BK=32 exactly (bit-identical sums).
// Doubles outstanding loads/wave -> ~2x attained BW (outstanding-limited).
__device__ __forceinline__ void mfma_loop64(
    const u16* __restrict__ Ab, size_t pa,
    const u16* __restrict__ Bb, size_t pb,
    int K, u16* sA, u16* sB, f32x4 (&acc)[4][2])
{
    const int tid = threadIdx.x;
    const int l = tid & 63, wv = tid >> 6;
    const int m16 = l & 15, k8 = l >> 4;
    const int kc = (tid & 3) * 8;
    const size_t ra0 = (size_t)(tid >> 2) * pa + kc;
    const size_t rb0 = (size_t)(tid >> 2) * pb + kc;
    const size_t rb1 = rb0 + 64 * pb;
    const int aO = m16 * 32 + k8 * 8;
    const int bO = (wv * 32 + m16) * 32 + k8 * 8;

#define STG64(KT, BUF) do {                                                    \
    gload16(Ab + ra0 + (KT),      sA + (BUF) * 4096 + tid * 8);                \
    gload16(Ab + ra0 + (KT) + 32, sA + (BUF) * 4096 + 2048 + tid * 8);         \
    gload16(Bb + rb0 + (KT),      sB + (BUF) * 8192 + tid * 8);                \
    gload16(Bb + rb1 + (KT),      sB + (BUF) * 8192 + (tid + 256) * 8);        \
    gload16(Bb + rb0 + (KT) + 32, sB + (BUF) * 8192 + 4096 + tid * 8);         \
    gload16(Bb + rb1 + (KT) + 32, sB + (BUF) * 8192 + 4096 + (tid + 256) * 8); \
} while (0)

    STG64(0, 0);
    int cur = 0;
    for (int kt = 0; kt < K; kt += 64) {
        __builtin_amdgcn_s_barrier();            // b1: all done reading buf[nx]
        const int nx = cur ^ 1;
        if (kt + 64 < K) {
            STG64(kt + 64, nx);
            asm volatile("s_waitcnt vmcnt(6)" ::: "memory");   // tile-kt landed; 6 in flight
        } else {
            asm volatile("s_waitcnt vmcnt(0)" ::: "memory");
        }
        __builtin_amdgcn_s_barrier();            // b2
        const u16* cA = sA + cur * 4096;
        const u16* cB = sB + cur * 8192;
#pragma unroll
        for (int h = 0; h < 2; h++) {
            bf16x8 af[4], bv[2];
#pragma unroll
            for (int i = 0; i < 4; i++) af[i] = *(const bf16x8*)(cA + h * 2048 + aO + i * 512);
#pragma unroll
            for (int j = 0; j < 2; j++) bv[j] = *(const bf16x8*)(cB + h * 4096 + bO + j * 512);
#pragma unroll
            for (int i = 0; i < 4; i++)
#pragma unroll
                for (int j = 0; j < 2; j++)
                    acc[i][j] = __builtin_amdgcn_mfma_f32_16x16x32_bf16(af[i], bv[j], acc[i][j], 0, 0, 0);
        }
        cur = nx;
    }
#undef STG64
}

// ---------------- conversion + softmax(w) ----------------
__global__ __launch_bounds__(256) void cvt6(
    const float* __restrict__ opW1, u16* __restrict__ w1b,
    const float* __restrict__ opW2, u16* __restrict__ w2b,
    const float* __restrict__ Wp,   u16* __restrict__ wpb,
    const float* __restrict__ phW,  u16* __restrict__ phwb,
    const float* __restrict__ rW1,  u16* __restrict__ rw1b,
    const float* __restrict__ op_logits, float* __restrict__ wbuf)
{
    if (blockIdx.x == 0 && threadIdx.x < 12) {
        const int t = threadIdx.x;
        float l0 = op_logits[t*3+0], l1 = op_logits[t*3+1], l2 = op_logits[t*3+2];
        float mx = fmaxf(l0, fmaxf(l1, l2));
        float e0 = expf(l0-mx), e1 = expf(l1-mx), e2 = expf(l2-mx);
        float inv = 1.f / (e0 + e1 + e2);
        wbuf[t*3+0] = e0*inv; wbuf[t*3+1] = e1*inv; wbuf[t*3+2] = e2*inv;
    }
    int i = (blockIdx.x * 256 + threadIdx.x) * 4;
    const float* s; u16* d;
    if (i < 9437184)                    { s = opW1; d = w1b; }
    else if ((i -= 9437184) < 9437184)  { s = opW2; d = w2b; }
    else if ((i -= 9437184) < 524288)   { s = Wp;   d = wpb; }
    else if ((i -= 524288)  < 524288)   { s = phW;  d = phwb; }
    else {
        i -= 524288;  // [0, 262144): rW1 cols 0..511 of 519
        int row = i >> 9, j = i & 511;
        const float* sr = rW1 + (size_t)row * 519 + j;
        u16x4 o = { f2bf(sr[0]), f2bf(sr[1]), f2bf(sr[2]), f2bf(sr[3]) };
        *(u16x4*)(rw1b + i) = o;
        return;
    }
    f32x4 v = *(const f32x4*)(s + i);
    u16x4 o = { f2bf(v[0]), f2bf(v[1]), f2bf(v[2]), f2bf(v[3]) };
    *(u16x4*)(d + i) = o;
}

// ---------------- G1: xp = x @ Wp^T + bp -> bf16 ----------------
// 64x128 tiles; 1D grid 768 with XCD swizzle. 2-deep A-register prefetch.
#define XP_STEP(KT, REG, CUR) do {                                              \
    __builtin_amdgcn_s_barrier();                                               \
    gload16(Bb + rb0 + (KT) + 32, sB + (1-(CUR)) * 4096 + tid * 8);             \
    gload16(Bb + rb1 + (KT) + 32, sB + (1-(CUR)) * 4096 + (tid + 256) * 8);     \
    { u16x8 c_;                                                                 \
      _Pragma("unroll") for (int j_ = 0; j_ < 8; j_++) c_[j_] = f2bf(REG[j_]);  \
      *(u16x8*)(sA + (1-(CUR)) * 2048 + tid * 8) = c_; }                        \
    REG = *(const f32x8*)(xrow + (((KT) + 96) & 1023));                         \
    asm volatile("s_waitcnt lgkmcnt(0)" ::: "memory");                          \
    asm volatile("s_waitcnt vmcnt(4)" ::: "memory");                            \
    __builtin_amdgcn_s_barrier();                                               \
    { const u16* cA_ = sA + (CUR) * 2048; const u16* cB_ = sB + (CUR) * 4096;   \
      bf16x8 af_[4], bv_[2];                                                    \
      _Pragma("unroll") for (int i_ = 0; i_ < 4; i_++)                          \
          af_[i_] = *(const bf16x8*)(cA_ + aO + i_ * 512);                      \
      _Pragma("unroll") for (int j_ = 0; j_ < 2; j_++)                          \
          bv_[j_] = *(const bf16x8*)(cB_ + bO + j_ * 512);                      \
      _Pragma("unroll") for (int i_ = 0; i_ < 4; i_++)                          \
      _Pragma("unroll") for (int j_ = 0; j_ < 2; j_++)                          \
          acc[i_][j_] = __builtin_amdgcn_mfma_f32_16x16x32_bf16(                \
              af_[i_], bv_[j_], acc[i_][j_], 0, 0, 0); }                        \
} while (0)

__global__ __launch_bounds__(256) void kgemm_xp(
    const float* __restrict__ x, const u16* __restrict__ wpb,
    const float* __restrict__ bp, u16* __restrict__ xpb)
{
    __shared__ u16 sA[4096], sB[8192];           // 2x2048 / 2x4096
    const int id = blockIdx.x;                   // 768 blocks
    const int cb = (id >> 3) & 3;                // col block 0..3
    const int yb = (id & 7) + ((id >> 5) << 3);  // row block 0..191
    const int rowBase = yb * 64, colBase = cb * 128;
    const int tid = threadIdx.x, l = tid & 63, wv = tid >> 6;
    const int m16 = l & 15, k8 = l >> 4;
    const int kc = (tid & 3) * 8;
    const float* xrow = x + (size_t)(rowBase + (tid >> 2)) * 1024 + kc;
    const u16* Bb = wpb + (size_t)colBase * 1024;
    const size_t rb0 = (size_t)(tid >> 2) * 1024 + kc;
    const size_t rb1 = rb0 + 64 * 1024;
    const int aO = m16 * 32 + k8 * 8;
    const int bO = (wv * 32 + m16) * 32 + k8 * 8;
    f32x4 acc[4][2];
#pragma unroll
    for (int i = 0; i < 4; i++)
#pragma unroll
        for (int j = 0; j < 2; j++) acc[i][j] = (f32x4){0.f,0.f,0.f,0.f};

    // prologue: tile0 -> buf0; A(1),A(2) left in flight in rEv/rOd
    gload16(Bb + rb0, sB + tid * 8);
    gload16(Bb + rb1, sB + (tid + 256) * 8);
    {
        f32x8 a0 = *(const f32x8*)(xrow);        // auto-wait drains B(0) too (once)
        u16x8 c;
#pragma unroll
        for (int j = 0; j < 8; j++) c[j] = f2bf(a0[j]);
        *(u16x8*)(sA + tid * 8) = c;
    }
    f32x8 rEv = *(const f32x8*)(xrow + 32);      // A(1), consumed at t=0
    f32x8 rOd = *(const f32x8*)(xrow + 64);      // A(2), consumed at t=1
    asm volatile("s_waitcnt lgkmcnt(0)" ::: "memory");

    for (int kt = 0; kt < 960; kt += 64) {       // t = 0..29 (pairs)
        XP_STEP(kt, rEv, 0);
        XP_STEP(kt + 32, rOd, 1);
    }
    XP_STEP(960, rEv, 0);                        // t = 30
    // t = 31 (cur = 1): nothing left to stage
    __builtin_amdgcn_s_barrier();
    asm volatile("s_waitcnt vmcnt(0) lgkmcnt(0)" ::: "memory");
    __builtin_amdgcn_s_barrier();
    {
        const u16* cA = sA + 2048;
        const u16* cB = sB + 4096;
        bf16x8 af[4], bv[2];
#pragma unroll
        for (int i = 0; i < 4; i++) af[i] = *(const bf16x8*)(cA + aO + i * 512);
#pragma unroll
        for (int j = 0; j < 2; j++) bv[j] = *(const bf16x8*)(cB + bO + j * 512);
#pragma unroll
        for (int i = 0; i < 4; i++)
#pragma unroll
            for (int j = 0; j < 2; j++)
                acc[i][j] = __builtin_amdgcn_mfma_f32_16x16x32_bf16(af[i], bv[j], acc[i][j], 0, 0, 0);
    }
#pragma unroll
    for (int in = 0; in < 2; in++) {
        const int gc = colBase + wv * 32 + in * 16 + m16;
        const float bv = bp[gc];
#pragma unroll
        for (int im = 0; im < 4; im++) {
            const int gr = rowBase + im * 16 + k8 * 4;
#pragma unroll
            for (int r = 0; r < 4; r++)
                xpb[(size_t)(gr + r) * 512 + gc] = f2bf(acc[im][in][r] + bv);
        }
    }
}

// ---------------- G2: h1[t,k] = relu(xg @ W1^T + b1) -> bf16 ----------------
__global__ __launch_bounds__(256) void kgemm_h1(
    const u16* __restrict__ xpb, const u16* __restrict__ w1b,
    const float* __restrict__ opb1, u16* __restrict__ h1b)
{
    __shared__ u16 sA[8192], sB[8192];
    const int id = blockIdx.x;
    const int seg = id >> 5, i = id & 31, t = seg / 3;
    const int xb = i & 3;                        // = xcd & 3 -> B col-tile per XCD
    const int yb = (i >> 3) + ((i >> 2) & 1) * 4;
    const int rowBase = yb * 128, colBase = xb * 128;
    f32x4 acc[4][4]; zero_acc(acc);
    // A row gi -> memory row gi*12 + t  (pitch 12*512)
    mfma_loop(xpb + (size_t)rowBase * 6144 + (size_t)t * 512, 6144,
              w1b + (size_t)seg * 262144 + (size_t)colBase * 512, 512, 512, sA, sB, acc);
    const int tid = threadIdx.x, l = tid & 63, wv = tid >> 6;
    const int wm = (wv >> 1) * 64, wn = (wv & 1) * 64, m16 = l & 15, k8 = l >> 4;
    u16* hseg = h1b + (size_t)seg * 524288;
#pragma unroll
    for (int in = 0; in < 4; in++) {
        const int gc = colBase + wn + in * 16 + m16;
        const float bv = opb1[seg * 512 + gc];
#pragma unroll
        for (int im = 0; im < 4; im++) {
            const int gr = rowBase + wm + im * 16 + k8 * 4;
#pragma unroll
            for (int r = 0; r < 4; r++)
                hseg[(size_t)(gr + r) * 512 + gc] = f2bf(fmaxf(acc[im][in][r] + bv, 0.f));
        }
    }
}

// ------- G3: out[t] = sum_k w[t,k]*relu(h1 @ W2^T + b2) -> f32 + bf16 -------
__global__ __launch_bounds__(256) void kgemm_out(
    const u16* __restrict__ h1b, const u16* __restrict__ w2b,
    const float* __restrict__ opb2, const float* __restrict__ wbuf,
    float* __restrict__ outF, u16* __restrict__ outb)
{
    __shared__ u16 sA[8192], sB[16384];          // BK=64: 2x4096 / 2x8192
    const int id = blockIdx.x;
    const int t = id >> 6, i = id & 63;
    const int a = i & 1, b2i = (i >> 1) & 3, q = i >> 3;
    const int xb = 2 * a + (q & 1), yb = 4 * b2i + (q >> 1);
    const int rowBase = yb * 64, colBase = xb * 128;
    const int tid = threadIdx.x, l = tid & 63, wv = tid >> 6;
    const int m16 = l & 15, k8 = l >> 4;
    float oac[4][2][4];
#pragma unroll
    for (int i1 = 0; i1 < 4; i1++)
#pragma unroll
        for (int j = 0; j < 2; j++)
#pragma unroll
            for (int r = 0; r < 4; r++) oac[i1][j][r] = 0.f;

    for (int kk = 0; kk < 3; kk++) {
        const int seg = t * 3 + kk;
        f32x4 acc[4][2];
#pragma unroll
        for (int i1 = 0; i1 < 4; i1++)
#pragma unroll
            for (int j = 0; j < 2; j++) acc[i1][j] = (f32x4){0.f,0.f,0.f,0.f};
        mfma_loop64(h1b + ((size_t)seg * 1024 + rowBase) * 512, 512,
                    w2b + (size_t)seg * 262144 + (size_t)colBase * 512, 512, 512, sA, sB, acc);
        const float wk = wbuf[seg];
#pragma unroll
        for (int in = 0; in < 2; in++) {
            const float bv = opb2[seg * 512 + colBase + wv * 32 + in * 16 + m16];
#pragma unroll
            for (int im = 0; im < 4; im++)
#pragma unroll
                for (int r = 0; r < 4; r++)
                    oac[im][in][r] += wk * fmaxf(acc[im][in][r] + bv, 0.f);
        }
    }
#pragma unroll
    for (int im = 0; im < 4; im++)
#pragma unroll
        for (int r = 0; r < 4; r++) {
            const int gi = rowBase + im * 16 + k8 * 4 + r;
            const size_t b = (size_t)gi * 12 + t;   // scatter back to patch order
#pragma unroll
            for (int in = 0; in < 2; in++) {
                const int gc = colBase + wv * 32 + in * 16 + m16;
                const float v = oac[im][in][r];
                outF[b * 512 + gc] = v;
                outb[b * 512 + gc] = f2bf(v);
            }
        }
}

// ------- G4+G5 fused: pred = out @ phW^T + phb  |  rh = relu(out @ rW1^T + bias_rh) -------
__global__ __launch_bounds__(256) void kgemm_predrh(
    const u16* __restrict__ outb, const u16* __restrict__ phwb,
    const float* __restrict__ phb, const u16* __restrict__ rw1b,
    const float* __restrict__ bias_rh, float* __restrict__ outPred,
    u16* __restrict__ rhb)
{
    __shared__ u16 sA[8192], sB[8192];
    const int id = blockIdx.x;
    const int j = id >> 3;
    const int bz = j % 12;                        // 0..7 pred colblocks, 8..11 rh
    const int yb = (id & 7) + (j / 12) * 8;       // 0..95
    const int rowBase = yb * 128;
    const bool isPred = bz < 8;
    const int colBase = (isPred ? bz : bz - 8) * 128;
    const u16* Bb = isPred ? (phwb + (size_t)colBase * 512)
                           : (rw1b + (size_t)colBase * 512);
    f32x4 acc[4][4]; zero_acc(acc);
    mfma_loop(outb + (size_t)rowBase * 512, 512, Bb, 512, 512, sA, sB, acc);
    const int tid = threadIdx.x, l = tid & 63, wv = tid >> 6;
    const int wm = (wv >> 1) * 64, wn = (wv & 1) * 64, m16 = l & 15, k8 = l >> 4;
    if (isPred) {
#pragma unroll
        for (int in = 0; in < 4; in++) {
            const int gc = colBase + wn + in * 16 + m16;
            const float bv = phb[gc];
#pragma unroll
            for (int im = 0; im < 4; im++) {
                const int gr = rowBase + wm + im * 16 + k8 * 4;
#pragma unroll
                for (int r = 0; r < 4; r++)
                    outPred[(size_t)(gr + r) * 1024 + gc] = acc[im][in][r] + bv;
            }
        }
    } else {
#pragma unroll
        for (int in = 0; in < 4; in++) {
            const int gc = colBase + wn + in * 16 + m16;
#pragma unroll
            for (int im = 0; im < 4; im++) {
                const int gr = rowBase + wm + im * 16 + k8 * 4;
#pragma unroll
                for (int r = 0; r < 4; r++) {
                    const int b = gr + r;
                    const float bv = bias_rh[(b % 12) * 512 + gc];
                    rhb[(size_t)b * 512 + gc] = f2bf(fmaxf(acc[im][in][r] + bv, 0.f));
                }
            }
        }
    }
}

// ---------------- per-group streaming reductions -> per-wave partials ----------------
// quarter-split: 4096 waves, each handles 3 of the 12 t-rows of one group.
__global__ __launch_bounds__(256) void rowred(
    const float* __restrict__ outF, const u16* __restrict__ xpb,
    const float* __restrict__ noise, float* __restrict__ partials)
{
    const int tid = threadIdx.x, l = tid & 63, wv = tid >> 6;
    const int gw = blockIdx.x * 4 + wv;          // 0..4095
    const int g = gw >> 2, q = gw & 3;
    const size_t base = (size_t)g * 12 * 512 + l * 8;
    float* pout = partials + (size_t)g * 60 + q * 15;
#pragma unroll
    for (int t0 = 0; t0 < 3; t0++) {
        const int t = q * 3 + t0;
        const size_t off = base + (size_t)t * 512;
        f32x8 ov = *(const f32x8*)(outF + off);
        f32x8 nv = *(const f32x8*)(noise + off);
        u16x8 xv = *(const u16x8*)(xpb + off);
        float s1 = 0, s2 = 0, s3 = 0, s4 = 0;
#pragma unroll
        for (int j = 0; j < 8; j++) {
            float xg = bf2f(xv[j]);
            float o = ov[j];
            float d = o - xg;
            s1 += d * d; s2 += xg * xg; s3 += fabsf(o); s4 += nv[j] * nv[j];
        }
#pragma unroll
        for (int off2 = 32; off2 > 0; off2 >>= 1) {
            s1 += __shfl_xor(s1, off2);
            s2 += __shfl_xor(s2, off2);
            s3 += __shfl_xor(s3, off2);
            s4 += __shfl_xor(s4, off2);
        }
        if (l < 5) {
            float v = (l == 0) ? s1 : (l == 1) ? s2 : (l == 2) ? s3
                    : (l == 3) ? s4 : s1 * s1;
            pout[t0 * 5 + l] = v;
        }
    }
}

// ---------------- partial-reduce + signals -> decision + folded routing bias ----------------
__global__ __launch_bounds__(256) void sig_kernel(
    const float* __restrict__ op_logits, const float* __restrict__ id_emb,
    const float* __restrict__ rW1, const float* __restrict__ rb1,
    const float* __restrict__ gW1, const float* __restrict__ gb1,
    const float* __restrict__ gW2, const float* __restrict__ gb2,
    const float* __restrict__ partials, float* __restrict__ bias_rh,
    float* __restrict__ outDec)
{
    const int t = blockIdx.x, tid = threadIdx.x;
    __shared__ float sig[7], ex7[7], gch[512], red[256], accv[5];
    float a[5] = {0.f, 0.f, 0.f, 0.f, 0.f};
    for (int g = tid; g < 1024; g += 256) {
        const float* p = partials + (size_t)g * 60 + t * 5;
#pragma unroll
        for (int s = 0; s < 5; s++) a[s] += p[s];
    }
#pragma unroll
    for (int s = 0; s < 5; s++) {
        red[tid] = a[s]; __syncthreads();
        for (int k = 128; k > 0; k >>= 1) { if (tid < k) red[tid] += red[tid + k]; __syncthreads(); }
        if (tid == 0) accv[s] = red[0];
        __syncthreads();
    }
    if (tid == 0) {
        float l0 = op_logits[t*3+0], l1 = op_logits[t*3+1], l2 = op_logits[t*3+2];
        float mx = fmaxf(l0, fmaxf(l1, l2));
        float e0 = expf(l0-mx), e1 = expf(l1-mx), e2 = expf(l2-mx);
        float es = e0 + e1 + e2;
        float w0 = e0/es, w1 = e1/es, w2 = e2/es;
        float mean = (w0 + w1 + w2) * (1.f/3.f);
        float var = ((w0-mean)*(w0-mean) + (w1-mean)*(w1-mean) + (w2-mean)*(w2-mean)) * 0.5f;
        float conflict = sqrtf(var);
        float inv_s = 1.f / (w0 + w1 + w2 + 1e-6f);
        float u0 = w0*inv_s, u1 = w1*inv_s, u2 = w2*inv_s;
        float ent = -(u0*logf(fmaxf(u0,1e-6f)) + u1*logf(fmaxf(u1,1e-6f)) + u2*logf(fmaxf(u2,1e-6f)));
        const float inv = 1.f / (1024.f * 512.f);
        float plast = accv[0] * inv;                 // pred_err mean == last_plasticity
        float nov   = accv[1] * inv;
        float spars = accv[2] * inv;
        float plasticity = 1e-4f * accv[3] * inv;
        float pe2 = accv[4] * (1.f / (1024.f * 512.f * 512.f));
        float na = 0.01f * plast;
        float rvar = pe2 - 2.f*na*plast + na*na;
        sig[0]=plasticity; sig[1]=nov; sig[2]=plast; sig[3]=ent; sig[4]=spars; sig[5]=-plast; sig[6]=rvar;
        ex7[0]=id_emb[t*4+0]; ex7[1]=id_emb[t*4+1]; ex7[2]=id_emb[t*4+2]; ex7[3]=id_emb[t*4+3];
        ex7[4]=nov; ex7[5]=conflict; ex7[6]=plast;
    }
    __syncthreads();
    for (int h = tid; h < 512; h += 256) {
        float aa = gb1[t*512 + h];
#pragma unroll
        for (int j = 0; j < 7; j++) aa += gW1[(t*512 + h)*7 + j] * sig[j];
        gch[h] = fmaxf(aa, 0.f);
        float bb = rb1[h];
#pragma unroll
        for (int e = 0; e < 7; e++) bb += ex7[e] * rW1[(size_t)h * 519 + 512 + e];
        bias_rh[t*512 + h] = bb;
    }
    __syncthreads();
    float p0 = 0.f, p1 = 0.f;
    for (int h = tid; h < 512; h += 256) {
        p0 += gW2[(t*2 + 0)*512 + h] * gch[h];
        p1 += gW2[(t*2 + 1)*512 + h] * gch[h];
    }
    red[tid] = p0; __syncthreads();
    for (int s = 128; s > 0; s >>= 1) { if (tid < s) red[tid] += red[tid + s]; __syncthreads(); }
    if (tid == 0) outDec[t*2 + 0] = red[0] + gb2[t*2 + 0];
    __syncthreads();
    red[tid] = p1; __syncthreads();
    for (int s = 128; s > 0; s >>= 1) { if (tid < s) red[tid] += red[tid + s]; __syncthreads(); }
    if (tid == 0) outDec[t*2 + 1] = red[0] + gb2[t*2 + 1];
}

// ---------------- logits = rh @ rW2^T + rb2 (one wave per row) ----------------
__global__ __launch_bounds__(256) void logits_kernel(
    const u16* __restrict__ rhb, const float* __restrict__ rW2,
    const float* __restrict__ rb2, float* __restrict__ outLg)
{
    __shared__ float T2[512 * 13];
    __shared__ float rb2s[16];
    const int tid = threadIdx.x;
    for (int i = tid; i < 6656; i += 256) {
        int o = i >> 9, j = i & 511;
        T2[j * 13 + o] = rW2[i];    // transposed+13-pitch: conflict-free reads
    }
    if (tid < 13) rb2s[tid] = rb2[tid];
    __syncthreads();
    const int l = tid & 63, wv = tid >> 6;
    const size_t b = (size_t)blockIdx.x * 4 + wv;
    const u16* rrow = rhb + b * 512;
    float rv[8];
#pragma unroll
    for (int jj = 0; jj < 8; jj++) rv[jj] = bf2f(rrow[l + 64 * jj]);
    float p[13];
#pragma unroll
    for (int o = 0; o < 13; o++) p[o] = 0.f;
#pragma unroll
    for (int jj = 0; jj < 8; jj++) {
        const float* tp = T2 + (l + 64 * jj) * 13;
#pragma unroll
        for (int o = 0; o < 13; o++) p[o] += rv[jj] * tp[o];
    }
#pragma unroll
    for (int o = 0; o < 13; o++) {
#pragma unroll
        for (int off = 32; off > 0; off >>= 1) p[o] += __shfl_xor(p[o], off);
    }
    if (l == 0) {
        float* orow = outLg + b * 13;
#pragma unroll
        for (int o = 0; o < 13; o++) orow[o] = p[o] + rb2s[o];
    }
}

extern "C" void kernel_launch(void* const* d_in, const int* in_sizes, int n_in,
                              void* d_out, int out_size, void* d_ws, size_t ws_size,
                              hipStream_t stream)
{
    const float* x         = (const float*)d_in[0];
    const float* Wp        = (const float*)d_in[1];
    const float* bp        = (const float*)d_in[2];
    const float* opW1      = (const float*)d_in[3];
    const float* opb1      = (const float*)d_in[4];
    const float* opW2      = (const float*)d_in[5];
    const float* opb2      = (const float*)d_in[6];
    const float* op_logits = (const float*)d_in[7];
    const float* id_emb    = (const float*)d_in[8];
    const float* rW1       = (const float*)d_in[9];
    const float* rb1       = (const float*)d_in[10];
    const float* rW2       = (const float*)d_in[11];
    const float* rb2       = (const float*)d_in[12];
    const float* gW1       = (const float*)d_in[13];
    const float* gb1       = (const float*)d_in[14];
    const float* gW2       = (const float*)d_in[15];
    const float* gb2       = (const float*)d_in[16];
    const float* phW       = (const float*)d_in[17];
    const float* phb       = (const float*)d_in[18];
    const float* noise     = (const float*)d_in[19];

    char* ws = (char*)d_ws;
    float* wbuf    = (float*)(ws + WS_W);
    float* bias_rh = (float*)(ws + WS_BIASRH);
    u16* wpb  = (u16*)(ws + WS_WPB);
    u16* phwb = (u16*)(ws + WS_PHWB);
    u16* rw1b = (u16*)(ws + WS_RW1B);
    u16* w1b  = (u16*)(ws + WS_W1B);
    u16* w2b  = (u16*)(ws + WS_W2B);
    u16* xpb  = (u16*)(ws + WS_XPB);
    u16* h1b  = (u16*)(ws + WS_H1B);
    u16* outb = (u16*)(ws + WS_OUTB);
    u16* rhb  = (u16*)(ws + WS_RHB);
    float* partials = (float*)(ws + WS_W1B);   // aliases w1b, dead after kgemm_h1

    float* outF    = (float*)d_out;
    float* outLg   = outF + OUT_LG;
    float* outPred = outF + OUT_PRED;
    float* outDec  = outF + OUT_DEC;

    cvt6<<<19712, 256, 0, stream>>>(opW1, w1b, opW2, w2b, Wp, wpb,
                                    phW, phwb, rW1, rw1b, op_logits, wbuf);
    kgemm_xp  <<<768,  256, 0, stream>>>(x, wpb, bp, xpb);
    kgemm_h1  <<<1152, 256, 0, stream>>>(xpb, w1b, opb1, h1b);
    kgemm_out <<<768,  256, 0, stream>>>(h1b, w2b, opb2, wbuf, outF, outb);
    rowred    <<<1024, 256, 0, stream>>>(outF, xpb, noise, partials);
    sig_kernel<<<12,   256, 0, stream>>>(op_logits, id_emb, rW1, rb1, gW1, gb1,
                                         gW2, gb2, partials, bias_rh, outDec);
    kgemm_predrh<<<1152, 256, 0, stream>>>(outb, phwb, phb, rw1b, bias_rh,
                                           outPred, rhb);
    logits_kernel<<<3072, 256, 0, stream>>>(rhb, rW2, rb2, outLg);
}

// Round 9
// 375.893 us; speedup vs baseline: 1.0564x; 1.0104x over previous
//
#include <hip/hip_runtime.h>

typedef unsigned short u16;
typedef float f32x4 __attribute__((ext_vector_type(4)));
typedef float f32x8 __attribute__((ext_vector_type(8)));
typedef u16   u16x4 __attribute__((ext_vector_type(4)));
typedef u16   u16x8 __attribute__((ext_vector_type(8)));
typedef __bf16 bf16x8 __attribute__((ext_vector_type(8)));

// ---------------- workspace layout (bytes) ----------------
#define WS_W       0u
#define WS_BIASRH  512u
#define WS_WPB     25600u
#define WS_PHWB    1074176u
#define WS_RW1B    2122752u
#define WS_W1B     2647040u
#define WS_W2B     21521408u
#define WS_XPB     40395776u
#define WS_H1B     52978688u
#define WS_OUTB    90727424u
#define WS_RHB     103310336u

#define OUT_LG   6291456
#define OUT_PRED 6451200
#define OUT_DEC  19034112

__device__ __forceinline__ u16 f2bf(float f) {
    unsigned u = __builtin_bit_cast(unsigned, f);
    return (u16)((u + 0x7FFFu + ((u >> 16) & 1u)) >> 16);
}
__device__ __forceinline__ float bf2f(u16 h) {
    return __builtin_bit_cast(float, (unsigned)h << 16);
}

typedef __attribute__((address_space(1))) void* gas1p;
typedef __attribute__((address_space(3))) void* las3p;
__device__ __forceinline__ void gload16(const u16* g, u16* l) {
    __builtin_amdgcn_global_load_lds((gas1p)(unsigned long long)g,
                                     (las3p)(unsigned)(unsigned long long)l,
                                     16, 0, 0);
}

__device__ __forceinline__ void zero_acc(f32x4 (&a)[4][4]) {
#pragma unroll
    for (int i = 0; i < 4; i++)
#pragma unroll
        for (int j = 0; j < 4; j++)
            a[i][j] = (f32x4){0.f, 0.f, 0.f, 0.f};
}

// 128x128 tile, BK=32, 4 waves (2x2 of 64x64). C = A * B^T.
// Double-buffered LDS, counted-vmcnt pipeline (1 tile in flight).
// VERIFIED structure (R3/R6 bench) — do not perturb scheduling.
__device__ __forceinline__ void mfma_loop(
    const u16* __restrict__ Ab, size_t pa,
    const u16* __restrict__ Bb, size_t pb,
    int K, u16* sA, u16* sB, f32x4 (&acc)[4][4])
{
    const int tid = threadIdx.x;
    const int l = tid & 63, wv = tid >> 6;
    const int wm = (wv >> 1) * 64, wn = (wv & 1) * 64;
    const int m16 = l & 15, k8 = l >> 4;
    const int kc = (tid & 3) * 8;
    const size_t ra0 = (size_t)(tid >> 2) * pa + kc;
    const size_t ra1 = ra0 + 64 * pa;
    const size_t rb0 = (size_t)(tid >> 2) * pb + kc;
    const size_t rb1 = rb0 + 64 * pb;
    const int aO = (wm + m16) * 32 + k8 * 8;
    const int bO = (wn + m16) * 32 + k8 * 8;
    gload16(Ab + ra0, sA + tid * 8);
    gload16(Ab + ra1, sA + (tid + 256) * 8);
    gload16(Bb + rb0, sB + tid * 8);
    gload16(Bb + rb1, sB + (tid + 256) * 8);
    int cur = 0;
    for (int kt = 0; kt < K; kt += 32) {
        __builtin_amdgcn_s_barrier();            // b1: all done reading buf[nx]
        const int nx = cur ^ 1;
        if (kt + 32 < K) {
            const int kn = kt + 32;
            gload16(Ab + ra0 + kn, sA + nx * 4096 + tid * 8);
            gload16(Ab + ra1 + kn, sA + nx * 4096 + (tid + 256) * 8);
            gload16(Bb + rb0 + kn, sB + nx * 4096 + tid * 8);
            gload16(Bb + rb1 + kn, sB + nx * 4096 + (tid + 256) * 8);
            asm volatile("s_waitcnt vmcnt(4)" ::: "memory");   // tile-kt landed; next 4 in flight
        } else {
            asm volatile("s_waitcnt vmcnt(0)" ::: "memory");
        }
        __builtin_amdgcn_s_barrier();            // b2: every wave's tile-kt loads landed
        const u16* cA = sA + cur * 4096;
        const u16* cB = sB + cur * 4096;
        bf16x8 af[4], bv[4];
#pragma unroll
        for (int i = 0; i < 4; i++) af[i] = *(const bf16x8*)(cA + aO + i * 512);
#pragma unroll
        for (int i = 0; i < 4; i++) bv[i] = *(const bf16x8*)(cB + bO + i * 512);
#pragma unroll
        for (int i = 0; i < 4; i++)
#pragma unroll
            for (int j = 0; j < 4; j++)
                acc[i][j] = __builtin_amdgcn_mfma_f32_16x16x32_bf16(af[i], bv[j], acc[i][j], 0, 0, 0);
        cur = nx;
    }
}

// 64x128 tile, BK=64, 4 waves side-by-side in N. Verified R7 structure:
// b1 -> stage nx (6 loads) -> vmcnt(6) -> b2 -> compute cur (two 32-K halves).
__device__ __forceinline__ void mfma_loop64(
    const u16* __restrict__ Ab, size_t pa,
    const u16* __restrict__ Bb, size_t pb,
    int K, u16* sA, u16* sB, f32x4 (&acc)[4][2])
{
    const int tid = threadIdx.x;
    const int l = tid & 63, wv = tid >> 6;
    const int m16 = l & 15, k8 = l >> 4;
    const int kc = (tid & 3) * 8;
    const size_t ra0 = (size_t)(tid >> 2) * pa + kc;
    const size_t rb0 = (size_t)(tid >> 2) * pb + kc;
    const size_t rb1 = rb0 + 64 * pb;
    const int aO = m16 * 32 + k8 * 8;
    const int bO = (wv * 32 + m16) * 32 + k8 * 8;

#define STG64(KT, BUF) do {                                                    \
    gload16(Ab + ra0 + (KT),      sA + (BUF) * 4096 + tid * 8);                \
    gload16(Ab + ra0 + (KT) + 32, sA + (BUF) * 4096 + 2048 + tid * 8);         \
    gload16(Bb + rb0 + (KT),      sB + (BUF) * 8192 + tid * 8);                \
    gload16(Bb + rb1 + (KT),      sB + (BUF) * 8192 + (tid + 256) * 8);        \
    gload16(Bb + rb0 + (KT) + 32, sB + (BUF) * 8192 + 4096 + tid * 8);         \
    gload16(Bb + rb1 + (KT) + 32, sB + (BUF) * 8192 + 4096 + (tid + 256) * 8); \
} while (0)

    STG64(0, 0);
    int cur = 0;
    for (int kt = 0; kt < K; kt += 64) {
        __builtin_amdgcn_s_barrier();            // b1: all done reading buf[nx]
        const int nx = cur ^ 1;
        if (kt + 64 < K) {
            STG64(kt + 64, nx);
            asm volatile("s_waitcnt vmcnt(6)" ::: "memory");   // tile-kt landed; 6 in flight
        } else {
            asm volatile("s_waitcnt vmcnt(0)" ::: "memory");
        }
        __builtin_amdgcn_s_barrier();            // b2
        const u16* cA = sA + cur * 4096;
        const u16* cB = sB + cur * 8192;
#pragma unroll
        for (int h = 0; h < 2; h++) {
            bf16x8 af[4], bv[2];
#pragma unroll
            for (int i = 0; i < 4; i++) af[i] = *(const bf16x8*)(cA + h * 2048 + aO + i * 512);
#pragma unroll
            for (int j = 0; j < 2; j++) bv[j] = *(const bf16x8*)(cB + h * 4096 + bO + j * 512);
#pragma unroll
            for (int i = 0; i < 4; i++)
#pragma unroll
                for (int j = 0; j < 2; j++)
                    acc[i][j] = __builtin_amdgcn_mfma_f32_16x16x32_bf16(af[i], bv[j], acc[i][j], 0, 0, 0);
        }
        cur = nx;
    }
#undef STG64
}

// ---------------- conversion + softmax(w) ----------------
// 8 elems/thread (f32x8 -> u16x8); all segment sizes divisible by 8.
__global__ __launch_bounds__(256) void cvt6(
    const float* __restrict__ opW1, u16* __restrict__ w1b,
    const float* __restrict__ opW2, u16* __restrict__ w2b,
    const float* __restrict__ Wp,   u16* __restrict__ wpb,
    const float* __restrict__ phW,  u16* __restrict__ phwb,
    const float* __restrict__ rW1,  u16* __restrict__ rw1b,
    const float* __restrict__ op_logits, float* __restrict__ wbuf)
{
    if (blockIdx.x == 0 && threadIdx.x < 12) {
        const int t = threadIdx.x;
        float l0 = op_logits[t*3+0], l1 = op_logits[t*3+1], l2 = op_logits[t*3+2];
        float mx = fmaxf(l0, fmaxf(l1, l2));
        float e0 = expf(l0-mx), e1 = expf(l1-mx), e2 = expf(l2-mx);
        float inv = 1.f / (e0 + e1 + e2);
        wbuf[t*3+0] = e0*inv; wbuf[t*3+1] = e1*inv; wbuf[t*3+2] = e2*inv;
    }
    int i = (blockIdx.x * 256 + threadIdx.x) * 8;
    const float* s; u16* d;
    if (i < 9437184)                    { s = opW1; d = w1b; }
    else if ((i -= 9437184) < 9437184)  { s = opW2; d = w2b; }
    else if ((i -= 9437184) < 524288)   { s = Wp;   d = wpb; }
    else if ((i -= 524288)  < 524288)   { s = phW;  d = phwb; }
    else {
        i -= 524288;  // [0, 262144): rW1 cols 0..511 of 519 (pitch 519 -> scalar reads)
        int row = i >> 9, j = i & 511;
        const float* sr = rW1 + (size_t)row * 519 + j;
        u16x8 o;
#pragma unroll
        for (int k = 0; k < 8; k++) o[k] = f2bf(sr[k]);
        *(u16x8*)(rw1b + i) = o;
        return;
    }
    f32x8 v = *(const f32x8*)(s + i);
    u16x8 o;
#pragma unroll
    for (int k = 0; k < 8; k++) o[k] = f2bf(v[k]);
    *(u16x8*)(d + i) = o;
}

// ---------------- G1: xp = x @ Wp^T + bp -> bf16 ----------------
// 64x128 tiles, BK=64; 1D grid 768 with XCD swizzle. Same verified sync family:
// b1 -> stage B(t+1) (4 gload_lds) + cvt A(t+1) regs -> reload A(t+2) regs ->
// lgkmcnt(0) -> vmcnt(6) -> b2 -> compute tile t (two 32-K halves).
// Binding wait: compiler auto-wait before cvt (A regs issued 1 iter earlier)
// which also drains B(t). LDS 48KB -> still 3 blocks/CU (grid-limited).
#define XP_STEP64(KT, CUR) do {                                                 \
    __builtin_amdgcn_s_barrier();                                               \
    gload16(Bb + rb0 + (KT) + 64, sB + (1-(CUR)) * 8192 + tid * 8);             \
    gload16(Bb + rb1 + (KT) + 64, sB + (1-(CUR)) * 8192 + (tid + 256) * 8);     \
    gload16(Bb + rb0 + (KT) + 96, sB + (1-(CUR)) * 8192 + 4096 + tid * 8);      \
    gload16(Bb + rb1 + (KT) + 96, sB + (1-(CUR)) * 8192 + 4096 + (tid + 256) * 8); \
    { u16x8 cl_, ch_;                                                           \
      _Pragma("unroll") for (int j_ = 0; j_ < 8; j_++) cl_[j_] = f2bf(rLo[j_]); \
      _Pragma("unroll") for (int j_ = 0; j_ < 8; j_++) ch_[j_] = f2bf(rHi[j_]); \
      *(u16x8*)(sA + (1-(CUR)) * 4096 + tid * 8) = cl_;                         \
      *(u16x8*)(sA + (1-(CUR)) * 4096 + 2048 + tid * 8) = ch_; }                \
    rLo = *(const f32x8*)(xrow + (((KT) + 128) & 1023));                        \
    rHi = *(const f32x8*)(xrow + (((KT) + 160) & 1023));                        \
    asm volatile("s_waitcnt lgkmcnt(0)" ::: "memory");                          \
    asm volatile("s_waitcnt vmcnt(6)" ::: "memory");                            \
    __builtin_amdgcn_s_barrier();                                               \
    { const u16* cA_ = sA + (CUR) * 4096; const u16* cB_ = sB + (CUR) * 8192;   \
      _Pragma("unroll") for (int h_ = 0; h_ < 2; h_++) {                        \
        bf16x8 af_[4], bv_[2];                                                  \
        _Pragma("unroll") for (int i_ = 0; i_ < 4; i_++)                        \
            af_[i_] = *(const bf16x8*)(cA_ + h_ * 2048 + aO + i_ * 512);        \
        _Pragma("unroll") for (int j_ = 0; j_ < 2; j_++)                        \
            bv_[j_] = *(const bf16x8*)(cB_ + h_ * 4096 + bO + j_ * 512);        \
        _Pragma("unroll") for (int i_ = 0; i_ < 4; i_++)                        \
        _Pragma("unroll") for (int j_ = 0; j_ < 2; j_++)                        \
            acc[i_][j_] = __builtin_amdgcn_mfma_f32_16x16x32_bf16(              \
                af_[i_], bv_[j_], acc[i_][j_], 0, 0, 0); } }                    \
} while (0)

__global__ __launch_bounds__(256) void kgemm_xp(
    const float* __restrict__ x, const u16* __restrict__ wpb,
    const float* __restrict__ bp, u16* __restrict__ xpb)
{
    __shared__ u16 sA[8192], sB[16384];          // BK=64: 2x4096 / 2x8192
    const int id = blockIdx.x;                   // 768 blocks
    const int cb = (id >> 3) & 3;                // col block 0..3
    const int yb = (id & 7) + ((id >> 5) << 3);  // row block 0..191
    const int rowBase = yb * 64, colBase = cb * 128;
    const int tid = threadIdx.x, l = tid & 63, wv = tid >> 6;
    const int m16 = l & 15, k8 = l >> 4;
    const int kc = (tid & 3) * 8;
    const float* xrow = x + (size_t)(rowBase + (tid >> 2)) * 1024 + kc;
    const u16* Bb = wpb + (size_t)colBase * 1024;
    const size_t rb0 = (size_t)(tid >> 2) * 1024 + kc;
    const size_t rb1 = rb0 + 64 * 1024;
    const int aO = m16 * 32 + k8 * 8;
    const int bO = (wv * 32 + m16) * 32 + k8 * 8;
    f32x4 acc[4][2];
#pragma unroll
    for (int i = 0; i < 4; i++)
#pragma unroll
        for (int j = 0; j < 2; j++) acc[i][j] = (f32x4){0.f,0.f,0.f,0.f};

    // prologue: tile0 (both halves) -> buf0; A(1) halves left in flight in rLo/rHi
    gload16(Bb + rb0,      sB + tid * 8);
    gload16(Bb + rb1,      sB + (tid + 256) * 8);
    gload16(Bb + rb0 + 32, sB + 4096 + tid * 8);
    gload16(Bb + rb1 + 32, sB + 4096 + (tid + 256) * 8);
    {
        f32x8 a0 = *(const f32x8*)(xrow);        // auto-wait drains B(0) too (once)
        f32x8 a1 = *(const f32x8*)(xrow + 32);
        u16x8 c0, c1;
#pragma unroll
        for (int j = 0; j < 8; j++) c0[j] = f2bf(a0[j]);
#pragma unroll
        for (int j = 0; j < 8; j++) c1[j] = f2bf(a1[j]);
        *(u16x8*)(sA + tid * 8) = c0;
        *(u16x8*)(sA + 2048 + tid * 8) = c1;
    }
    f32x8 rLo = *(const f32x8*)(xrow + 64);      // A(1) lo, consumed at t=0
    f32x8 rHi = *(const f32x8*)(xrow + 96);      // A(1) hi
    asm volatile("s_waitcnt lgkmcnt(0)" ::: "memory");

    for (int kt = 0; kt < 896; kt += 128) {      // t = 0..13 (pairs)
        XP_STEP64(kt, 0);
        XP_STEP64(kt + 64, 1);
    }
    XP_STEP64(896, 0);                           // t = 14, stages tile 15 -> buf1
    // t = 15 (cur = 1): nothing left to stage
    __builtin_amdgcn_s_barrier();
    asm volatile("s_waitcnt vmcnt(0) lgkmcnt(0)" ::: "memory");
    __builtin_amdgcn_s_barrier();
    {
        const u16* cA = sA + 4096;
        const u16* cB = sB + 8192;
#pragma unroll
        for (int h = 0; h < 2; h++) {
            bf16x8 af[4], bv[2];
#pragma unroll
            for (int i = 0; i < 4; i++) af[i] = *(const bf16x8*)(cA + h * 2048 + aO + i * 512);
#pragma unroll
            for (int j = 0; j < 2; j++) bv[j] = *(const bf16x8*)(cB + h * 4096 + bO + j * 512);
#pragma unroll
            for (int i = 0; i < 4; i++)
#pragma unroll
                for (int j = 0; j < 2; j++)
                    acc[i][j] = __builtin_amdgcn_mfma_f32_16x16x32_bf16(af[i], bv[j], acc[i][j], 0, 0, 0);
        }
    }
#pragma unroll
    for (int in = 0; in < 2; in++) {
        const int gc = colBase + wv * 32 + in * 16 + m16;
        const float bv = bp[gc];
#pragma unroll
        for (int im = 0; im < 4; im++) {
            const int gr = rowBase + im * 16 + k8 * 4;
#pragma unroll
            for (int r = 0; r < 4; r++)
                xpb[(size_t)(gr + r) * 512 + gc] = f2bf(acc[im][in][r] + bv);
        }
    }
}

// ---------------- G2: h1[t,k] = relu(xg @ W1^T + b1) -> bf16 ----------------
__global__ __launch_bounds__(256) void kgemm_h1(
    const u16* __restrict__ xpb, const u16* __restrict__ w1b,
    const float* __restrict__ opb1, u16* __restrict__ h1b)
{
    __shared__ u16 sA[8192], sB[8192];
    const int id = blockIdx.x;
    const int seg = id >> 5, i = id & 31, t = seg / 3;
    const int xb = i & 3;                        // = xcd & 3 -> B col-tile per XCD
    const int yb = (i >> 3) + ((i >> 2) & 1) * 4;
    const int rowBase = yb * 128, colBase = xb * 128;
    f32x4 acc[4][4]; zero_acc(acc);
    // A row gi -> memory row gi*12 + t  (pitch 12*512)
    mfma_loop(xpb + (size_t)rowBase * 6144 + (size_t)t * 512, 6144,
              w1b + (size_t)seg * 262144 + (size_t)colBase * 512, 512, 512, sA, sB, acc);
    const int tid = threadIdx.x, l = tid & 63, wv = tid >> 6;
    const int wm = (wv >> 1) * 64, wn = (wv & 1) * 64, m16 = l & 15, k8 = l >> 4;
    u16* hseg = h1b + (size_t)seg * 524288;
#pragma unroll
    for (int in = 0; in < 4; in++) {
        const int gc = colBase + wn + in * 16 + m16;
        const float bv = opb1[seg * 512 + gc];
#pragma unroll
        for (int im = 0; im < 4; im++) {
            const int gr = rowBase + wm + im * 16 + k8 * 4;
#pragma unroll
            for (int r = 0; r < 4; r++)
                hseg[(size_t)(gr + r) * 512 + gc] = f2bf(fmaxf(acc[im][in][r] + bv, 0.f));
        }
    }
}

// ------- G3: out[t] = sum_k w[t,k]*relu(h1 @ W2^T + b2) -> f32 + bf16 -------
__global__ __launch_bounds__(256) void kgemm_out(
    const u16* __restrict__ h1b, const u16* __restrict__ w2b,
    const float* __restrict__ opb2, const float* __restrict__ wbuf,
    float* __restrict__ outF, u16* __restrict__ outb)
{
    __shared__ u16 sA[8192], sB[16384];          // BK=64: 2x4096 / 2x8192
    const int id = blockIdx.x;
    const int t = id >> 6, i = id & 63;
    const int a = i & 1, b2i = (i >> 1) & 3, q = i >> 3;
    const int xb = 2 * a + (q & 1), yb = 4 * b2i + (q >> 1);
    const int rowBase = yb * 64, colBase = xb * 128;
    const int tid = threadIdx.x, l = tid & 63, wv = tid >> 6;
    const int m16 = l & 15, k8 = l >> 4;
    float oac[4][2][4];
#pragma unroll
    for (int i1 = 0; i1 < 4; i1++)
#pragma unroll
        for (int j = 0; j < 2; j++)
#pragma unroll
            for (int r = 0; r < 4; r++) oac[i1][j][r] = 0.f;

    for (int kk = 0; kk < 3; kk++) {
        const int seg = t * 3 + kk;
        f32x4 acc[4][2];
#pragma unroll
        for (int i1 = 0; i1 < 4; i1++)
#pragma unroll
            for (int j = 0; j < 2; j++) acc[i1][j] = (f32x4){0.f,0.f,0.f,0.f};
        mfma_loop64(h1b + ((size_t)seg * 1024 + rowBase) * 512, 512,
                    w2b + (size_t)seg * 262144 + (size_t)colBase * 512, 512, 512, sA, sB, acc);
        const float wk = wbuf[seg];
#pragma unroll
        for (int in = 0; in < 2; in++) {
            const float bv = opb2[seg * 512 + colBase + wv * 32 + in * 16 + m16];
#pragma unroll
            for (int im = 0; im < 4; im++)
#pragma unroll
                for (int r = 0; r < 4; r++)
                    oac[im][in][r] += wk * fmaxf(acc[im][in][r] + bv, 0.f);
        }
    }
#pragma unroll
    for (int im = 0; im < 4; im++)
#pragma unroll
        for (int r = 0; r < 4; r++) {
            const int gi = rowBase + im * 16 + k8 * 4 + r;
            const size_t b = (size_t)gi * 12 + t;   // scatter back to patch order
#pragma unroll
            for (int in = 0; in < 2; in++) {
                const int gc = colBase + wv * 32 + in * 16 + m16;
                const float v = oac[im][in][r];
                outF[b * 512 + gc] = v;
                outb[b * 512 + gc] = f2bf(v);
            }
        }
}

// ------- G4+G5 fused: pred = out @ phW^T + phb  |  rh = relu(out @ rW1^T + bias_rh) -------
__global__ __launch_bounds__(256) void kgemm_predrh(
    const u16* __restrict__ outb, const u16* __restrict__ phwb,
    const float* __restrict__ phb, const u16* __restrict__ rw1b,
    const float* __restrict__ bias_rh, float* __restrict__ outPred,
    u16* __restrict__ rhb)
{
    __shared__ u16 sA[8192], sB[8192];
    const int id = blockIdx.x;
    const int j = id >> 3;
    const int bz = j % 12;                        // 0..7 pred colblocks, 8..11 rh
    const int yb = (id & 7) + (j / 12) * 8;       // 0..95
    const int rowBase = yb * 128;
    const bool isPred = bz < 8;
    const int colBase = (isPred ? bz : bz - 8) * 128;
    const u16* Bb = isPred ? (phwb + (size_t)colBase * 512)
                           : (rw1b + (size_t)colBase * 512);
    f32x4 acc[4][4]; zero_acc(acc);
    mfma_loop(outb + (size_t)rowBase * 512, 512, Bb, 512, 512, sA, sB, acc);
    const int tid = threadIdx.x, l = tid & 63, wv = tid >> 6;
    const int wm = (wv >> 1) * 64, wn = (wv & 1) * 64, m16 = l & 15, k8 = l >> 4;
    if (isPred) {
#pragma unroll
        for (int in = 0; in < 4; in++) {
            const int gc = colBase + wn + in * 16 + m16;
            const float bv = phb[gc];
#pragma unroll
            for (int im = 0; im < 4; im++) {
                const int gr = rowBase + wm + im * 16 + k8 * 4;
#pragma unroll
                for (int r = 0; r < 4; r++)
                    outPred[(size_t)(gr + r) * 1024 + gc] = acc[im][in][r] + bv;
            }
        }
    } else {
#pragma unroll
        for (int in = 0; in < 4; in++) {
            const int gc = colBase + wn + in * 16 + m16;
#pragma unroll
            for (int im = 0; im < 4; im++) {
                const int gr = rowBase + wm + im * 16 + k8 * 4;
#pragma unroll
                for (int r = 0; r < 4; r++) {
                    const int b = gr + r;
                    const float bv = bias_rh[(b % 12) * 512 + gc];
                    rhb[(size_t)b * 512 + gc] = f2bf(fmaxf(acc[im][in][r] + bv, 0.f));
                }
            }
        }
    }
}

// ---------------- per-group streaming reductions -> per-wave partials ----------------
// quarter-split: 4096 waves, each handles 3 of the 12 t-rows of one group.
__global__ __launch_bounds__(256) void rowred(
    const float* __restrict__ outF, const u16* __restrict__ xpb,
    const float* __restrict__ noise, float* __restrict__ partials)
{
    const int tid = threadIdx.x, l = tid & 63, wv = tid >> 6;
    const int gw = blockIdx.x * 4 + wv;          // 0..4095
    const int g = gw >> 2, q = gw & 3;
    const size_t base = (size_t)g * 12 * 512 + l * 8;
    float* pout = partials + (size_t)g * 60 + q * 15;
#pragma unroll
    for (int t0 = 0; t0 < 3; t0++) {
        const int t = q * 3 + t0;
        const size_t off = base + (size_t)t * 512;
        f32x8 ov = *(const f32x8*)(outF + off);
        f32x8 nv = *(const f32x8*)(noise + off);
        u16x8 xv = *(const u16x8*)(xpb + off);
        float s1 = 0, s2 = 0, s3 = 0, s4 = 0;
#pragma unroll
        for (int j = 0; j < 8; j++) {
            float xg = bf2f(xv[j]);
            float o = ov[j];
            float d = o - xg;
            s1 += d * d; s2 += xg * xg; s3 += fabsf(o); s4 += nv[j] * nv[j];
        }
#pragma unroll
        for (int off2 = 32; off2 > 0; off2 >>= 1) {
            s1 += __shfl_xor(s1, off2);
            s2 += __shfl_xor(s2, off2);
            s3 += __shfl_xor(s3, off2);
            s4 += __shfl_xor(s4, off2);
        }
        if (l < 5) {
            float v = (l == 0) ? s1 : (l == 1) ? s2 : (l == 2) ? s3
                    : (l == 3) ? s4 : s1 * s1;
            pout[t0 * 5 + l] = v;
        }
    }
}

// ---------------- partial-reduce + signals -> decision + folded routing bias ----------------
__global__ __launch_bounds__(256) void sig_kernel(
    const float* __restrict__ op_logits, const float* __restrict__ id_emb,
    const float* __restrict__ rW1, const float* __restrict__ rb1,
    const float* __restrict__ gW1, const float* __restrict__ gb1,
    const float* __restrict__ gW2, const float* __restrict__ gb2,
    const float* __restrict__ partials, float* __restrict__ bias_rh,
    float* __restrict__ outDec)
{
    const int t = blockIdx.x, tid = threadIdx.x;
    __shared__ float sig[7], ex7[7], gch[512], red[256], accv[5];
    float a[5] = {0.f, 0.f, 0.f, 0.f, 0.f};
    for (int g = tid; g < 1024; g += 256) {
        const float* p = partials + (size_t)g * 60 + t * 5;
#pragma unroll
        for (int s = 0; s < 5; s++) a[s] += p[s];
    }
#pragma unroll
    for (int s = 0; s < 5; s++) {
        red[tid] = a[s]; __syncthreads();
        for (int k = 128; k > 0; k >>= 1) { if (tid < k) red[tid] += red[tid + k]; __syncthreads(); }
        if (tid == 0) accv[s] = red[0];
        __syncthreads();
    }
    if (tid == 0) {
        float l0 = op_logits[t*3+0], l1 = op_logits[t*3+1], l2 = op_logits[t*3+2];
        float mx = fmaxf(l0, fmaxf(l1, l2));
        float e0 = expf(l0-mx), e1 = expf(l1-mx), e2 = expf(l2-mx);
        float es = e0 + e1 + e2;
        float w0 = e0/es, w1 = e1/es, w2 = e2/es;
        float mean = (w0 + w1 + w2) * (1.f/3.f);
        float var = ((w0-mean)*(w0-mean) + (w1-mean)*(w1-mean) + (w2-mean)*(w2-mean)) * 0.5f;
        float conflict = sqrtf(var);
        float inv_s = 1.f / (w0 + w1 + w2 + 1e-6f);
        float u0 = w0*inv_s, u1 = w1*inv_s, u2 = w2*inv_s;
        float ent = -(u0*logf(fmaxf(u0,1e-6f)) + u1*logf(fmaxf(u1,1e-6f)) + u2*logf(fmaxf(u2,1e-6f)));
        const float inv = 1.f / (1024.f * 512.f);
        float plast = accv[0] * inv;                 // pred_err mean == last_plasticity
        float nov   = accv[1] * inv;
        float spars = accv[2] * inv;
        float plasticity = 1e-4f * accv[3] * inv;
        float pe2 = accv[4] * (1.f / (1024.f * 512.f * 512.f));
        float na = 0.01f * plast;
        float rvar = pe2 - 2.f*na*plast + na*na;
        sig[0]=plasticity; sig[1]=nov; sig[2]=plast; sig[3]=ent; sig[4]=spars; sig[5]=-plast; sig[6]=rvar;
        ex7[0]=id_emb[t*4+0]; ex7[1]=id_emb[t*4+1]; ex7[2]=id_emb[t*4+2]; ex7[3]=id_emb[t*4+3];
        ex7[4]=nov; ex7[5]=conflict; ex7[6]=plast;
    }
    __syncthreads();
    for (int h = tid; h < 512; h += 256) {
        float aa = gb1[t*512 + h];
#pragma unroll
        for (int j = 0; j < 7; j++) aa += gW1[(t*512 + h)*7 + j] * sig[j];
        gch[h] = fmaxf(aa, 0.f);
        float bb = rb1[h];
#pragma unroll
        for (int e = 0; e < 7; e++) bb += ex7[e] * rW1[(size_t)h * 519 + 512 + e];
        bias_rh[t*512 + h] = bb;
    }
    __syncthreads();
    float p0 = 0.f, p1 = 0.f;
    for (int h = tid; h < 512; h += 256) {
        p0 += gW2[(t*2 + 0)*512 + h] * gch[h];
        p1 += gW2[(t*2 + 1)*512 + h] * gch[h];
    }
    red[tid] = p0; __syncthreads();
    for (int s = 128; s > 0; s >>= 1) { if (tid < s) red[tid] += red[tid + s]; __syncthreads(); }
    if (tid == 0) outDec[t*2 + 0] = red[0] + gb2[t*2 + 0];
    __syncthreads();
    red[tid] = p1; __syncthreads();
    for (int s = 128; s > 0; s >>= 1) { if (tid < s) red[tid] += red[tid + s]; __syncthreads(); }
    if (tid == 0) outDec[t*2 + 1] = red[0] + gb2[t*2 + 1];
}

// ---------------- logits = rh @ rW2^T + rb2 (one wave per row) ----------------
__global__ __launch_bounds__(256) void logits_kernel(
    const u16* __restrict__ rhb, const float* __restrict__ rW2,
    const float* __restrict__ rb2, float* __restrict__ outLg)
{
    __shared__ float T2[512 * 13];
    __shared__ float rb2s[16];
    const int tid = threadIdx.x;
    for (int i = tid; i < 6656; i += 256) {
        int o = i >> 9, j = i & 511;
        T2[j * 13 + o] = rW2[i];    // transposed+13-pitch: conflict-free reads
    }
    if (tid < 13) rb2s[tid] = rb2[tid];
    __syncthreads();
    const int l = tid & 63, wv = tid >> 6;
    const size_t b = (size_t)blockIdx.x * 4 + wv;
    const u16* rrow = rhb + b * 512;
    float rv[8];
#pragma unroll
    for (int jj = 0; jj < 8; jj++) rv[jj] = bf2f(rrow[l + 64 * jj]);
    float p[13];
#pragma unroll
    for (int o = 0; o < 13; o++) p[o] = 0.f;
#pragma unroll
    for (int jj = 0; jj < 8; jj++) {
        const float* tp = T2 + (l + 64 * jj) * 13;
#pragma unroll
        for (int o = 0; o < 13; o++) p[o] += rv[jj] * tp[o];
    }
#pragma unroll
    for (int o = 0; o < 13; o++) {
#pragma unroll
        for (int off = 32; off > 0; off >>= 1) p[o] += __shfl_xor(p[o], off);
    }
    if (l == 0) {
        float* orow = outLg + b * 13;
#pragma unroll
        for (int o = 0; o < 13; o++) orow[o] = p[o] + rb2s[o];
    }
}

extern "C" void kernel_launch(void* const* d_in, const int* in_sizes, int n_in,
                              void* d_out, int out_size, void* d_ws, size_t ws_size,
                              hipStream_t stream)
{
    const float* x         = (const float*)d_in[0];
    const float* Wp        = (const float*)d_in[1];
    const float* bp        = (const float*)d_in[2];
    const float* opW1      = (const float*)d_in[3];
    const float* opb1      = (const float*)d_in[4];
    const float* opW2      = (const float*)d_in[5];
    const float* opb2      = (const float*)d_in[6];
    const float* op_logits = (const float*)d_in[7];
    const float* id_emb    = (const float*)d_in[8];
    const float* rW1       = (const float*)d_in[9];
    const float* rb1       = (const float*)d_in[10];
    const float* rW2       = (const float*)d_in[11];
    const float* rb2       = (const float*)d_in[12];
    const float* gW1       = (const float*)d_in[13];
    const float* gb1       = (const float*)d_in[14];
    const float* gW2       = (const float*)d_in[15];
    const float* gb2       = (const float*)d_in[16];
    const float* phW       = (const float*)d_in[17];
    const float* phb       = (const float*)d_in[18];
    const float* noise     = (const float*)d_in[19];

    char* ws = (char*)d_ws;
    float* wbuf    = (float*)(ws + WS_W);
    float* bias_rh = (float*)(ws + WS_BIASRH);
    u16* wpb  = (u16*)(ws + WS_WPB);
    u16* phwb = (u16*)(ws + WS_PHWB);
    u16* rw1b = (u16*)(ws + WS_RW1B);
    u16* w1b  = (u16*)(ws + WS_W1B);
    u16* w2b  = (u16*)(ws + WS_W2B);
    u16* xpb  = (u16*)(ws + WS_XPB);
    u16* h1b  = (u16*)(ws + WS_H1B);
    u16* outb = (u16*)(ws + WS_OUTB);
    u16* rhb  = (u16*)(ws + WS_RHB);
    float* partials = (float*)(ws + WS_W1B);   // aliases w1b, dead after kgemm_h1

    float* outF    = (float*)d_out;
    float* outLg   = outF + OUT_LG;
    float* outPred = outF + OUT_PRED;
    float* outDec  = outF + OUT_DEC;

    // 20185088 f32 elems / 2048 per block = 9856 blocks (exact)
    cvt6<<<9856, 256, 0, stream>>>(opW1, w1b, opW2, w2b, Wp, wpb,
                                   phW, phwb, rW1, rw1b, op_logits, wbuf);
    kgemm_xp  <<<768,  256, 0, stream>>>(x, wpb, bp, xpb);
    kgemm_h1  <<<1152, 256, 0, stream>>>(xpb, w1b, opb1, h1b);
    kgemm_out <<<768,  256, 0, stream>>>(h1b, w2b, opb2, wbuf, outF, outb);
    rowred    <<<1024, 256, 0, stream>>>(outF, xpb, noise, partials);
    sig_kernel<<<12,   256, 0, stream>>>(op_logits, id_emb, rW1, rb1, gW1, gb1,
                                         gW2, gb2, partials, bias_rh, outDec);
    kgemm_predrh<<<1152, 256, 0, stream>>>(outb, phwb, phb, rw1b, bias_rh,
                                           outPred, rhb);
    logits_kernel<<<3072, 256, 0, stream>>>(rhb, rW2, rb2, outLg);
}

// Round 10
// 369.403 us; speedup vs baseline: 1.0750x; 1.0176x over previous
//
#include <hip/hip_runtime.h>

typedef unsigned short u16;
typedef float f32x4 __attribute__((ext_vector_type(4)));
typedef float f32x8 __attribute__((ext_vector_type(8)));
typedef u16   u16x4 __attribute__((ext_vector_type(4)));
typedef u16   u16x8 __attribute__((ext_vector_type(8)));
typedef __bf16 bf16x8 __attribute__((ext_vector_type(8)));

// ---------------- workspace layout (bytes) ----------------
#define WS_W       0u
#define WS_BIASRH  512u
#define WS_WPB     25600u
#define WS_PHWB    1074176u
#define WS_RW1B    2122752u
#define WS_W1B     2647040u
#define WS_W2B     21521408u
#define WS_XPB     40395776u
#define WS_H1B     52978688u
#define WS_OUTB    90727424u
#define WS_RHB     103310336u

#define OUT_LG   6291456
#define OUT_PRED 6451200
#define OUT_DEC  19034112

__device__ __forceinline__ u16 f2bf(float f) {
    unsigned u = __builtin_bit_cast(unsigned, f);
    return (u16)((u + 0x7FFFu + ((u >> 16) & 1u)) >> 16);
}
__device__ __forceinline__ float bf2f(u16 h) {
    return __builtin_bit_cast(float, (unsigned)h << 16);
}

typedef __attribute__((address_space(1))) void* gas1p;
typedef __attribute__((address_space(3))) void* las3p;
__device__ __forceinline__ void gload16(const u16* g, u16* l) {
    __builtin_amdgcn_global_load_lds((gas1p)(unsigned long long)g,
                                     (las3p)(unsigned)(unsigned long long)l,
                                     16, 0, 0);
}

// 64x128 tile, BK=64, 4 waves side-by-side in N. VERIFIED R7/R8 structure:
// b1 -> stage nx (6 loads) -> vmcnt(6) -> b2 -> compute cur (two 32-K halves).
// Do not perturb scheduling.
__device__ __forceinline__ void mfma_loop64(
    const u16* __restrict__ Ab, size_t pa,
    const u16* __restrict__ Bb, size_t pb,
    int K, u16* sA, u16* sB, f32x4 (&acc)[4][2])
{
    const int tid = threadIdx.x;
    const int l = tid & 63, wv = tid >> 6;
    const int m16 = l & 15, k8 = l >> 4;
    const int kc = (tid & 3) * 8;
    const size_t ra0 = (size_t)(tid >> 2) * pa + kc;
    const size_t rb0 = (size_t)(tid >> 2) * pb + kc;
    const size_t rb1 = rb0 + 64 * pb;
    const int aO = m16 * 32 + k8 * 8;
    const int bO = (wv * 32 + m16) * 32 + k8 * 8;

#define STG64(KT, BUF) do {                                                    \
    gload16(Ab + ra0 + (KT),      sA + (BUF) * 4096 + tid * 8);                \
    gload16(Ab + ra0 + (KT) + 32, sA + (BUF) * 4096 + 2048 + tid * 8);         \
    gload16(Bb + rb0 + (KT),      sB + (BUF) * 8192 + tid * 8);                \
    gload16(Bb + rb1 + (KT),      sB + (BUF) * 8192 + (tid + 256) * 8);        \
    gload16(Bb + rb0 + (KT) + 32, sB + (BUF) * 8192 + 4096 + tid * 8);         \
    gload16(Bb + rb1 + (KT) + 32, sB + (BUF) * 8192 + 4096 + (tid + 256) * 8); \
} while (0)

    STG64(0, 0);
    int cur = 0;
    for (int kt = 0; kt < K; kt += 64) {
        __builtin_amdgcn_s_barrier();            // b1: all done reading buf[nx]
        const int nx = cur ^ 1;
        if (kt + 64 < K) {
            STG64(kt + 64, nx);
            asm volatile("s_waitcnt vmcnt(6)" ::: "memory");   // tile-kt landed; 6 in flight
        } else {
            asm volatile("s_waitcnt vmcnt(0)" ::: "memory");
        }
        __builtin_amdgcn_s_barrier();            // b2
        const u16* cA = sA + cur * 4096;
        const u16* cB = sB + cur * 8192;
#pragma unroll
        for (int h = 0; h < 2; h++) {
            bf16x8 af[4], bv[2];
#pragma unroll
            for (int i = 0; i < 4; i++) af[i] = *(const bf16x8*)(cA + h * 2048 + aO + i * 512);
#pragma unroll
            for (int j = 0; j < 2; j++) bv[j] = *(const bf16x8*)(cB + h * 4096 + bO + j * 512);
#pragma unroll
            for (int i = 0; i < 4; i++)
#pragma unroll
                for (int j = 0; j < 2; j++)
                    acc[i][j] = __builtin_amdgcn_mfma_f32_16x16x32_bf16(af[i], bv[j], acc[i][j], 0, 0, 0);
        }
        cur = nx;
    }
#undef STG64
}

// ---------------- conversion + softmax(w) ----------------
// 8 elems/thread (f32x8 -> u16x8); all segment sizes divisible by 8.
__global__ __launch_bounds__(256) void cvt6(
    const float* __restrict__ opW1, u16* __restrict__ w1b,
    const float* __restrict__ opW2, u16* __restrict__ w2b,
    const float* __restrict__ Wp,   u16* __restrict__ wpb,
    const float* __restrict__ phW,  u16* __restrict__ phwb,
    const float* __restrict__ rW1,  u16* __restrict__ rw1b,
    const float* __restrict__ op_logits, float* __restrict__ wbuf)
{
    if (blockIdx.x == 0 && threadIdx.x < 12) {
        const int t = threadIdx.x;
        float l0 = op_logits[t*3+0], l1 = op_logits[t*3+1], l2 = op_logits[t*3+2];
        float mx = fmaxf(l0, fmaxf(l1, l2));
        float e0 = expf(l0-mx), e1 = expf(l1-mx), e2 = expf(l2-mx);
        float inv = 1.f / (e0 + e1 + e2);
        wbuf[t*3+0] = e0*inv; wbuf[t*3+1] = e1*inv; wbuf[t*3+2] = e2*inv;
    }
    int i = (blockIdx.x * 256 + threadIdx.x) * 8;
    const float* s; u16* d;
    if (i < 9437184)                    { s = opW1; d = w1b; }
    else if ((i -= 9437184) < 9437184)  { s = opW2; d = w2b; }
    else if ((i -= 9437184) < 524288)   { s = Wp;   d = wpb; }
    else if ((i -= 524288)  < 524288)   { s = phW;  d = phwb; }
    else {
        i -= 524288;  // [0, 262144): rW1 cols 0..511 of 519 (pitch 519 -> scalar reads)
        int row = i >> 9, j = i & 511;
        const float* sr = rW1 + (size_t)row * 519 + j;
        u16x8 o;
#pragma unroll
        for (int k = 0; k < 8; k++) o[k] = f2bf(sr[k]);
        *(u16x8*)(rw1b + i) = o;
        return;
    }
    f32x8 v = *(const f32x8*)(s + i);
    u16x8 o;
#pragma unroll
    for (int k = 0; k < 8; k++) o[k] = f2bf(v[k]);
    *(u16x8*)(d + i) = o;
}

// ---------------- G1: xp = x @ Wp^T + bp -> bf16 (verified R8) ----------------
#define XP_STEP64(KT, CUR) do {                                                 \
    __builtin_amdgcn_s_barrier();                                               \
    gload16(Bb + rb0 + (KT) + 64, sB + (1-(CUR)) * 8192 + tid * 8);             \
    gload16(Bb + rb1 + (KT) + 64, sB + (1-(CUR)) * 8192 + (tid + 256) * 8);     \
    gload16(Bb + rb0 + (KT) + 96, sB + (1-(CUR)) * 8192 + 4096 + tid * 8);      \
    gload16(Bb + rb1 + (KT) + 96, sB + (1-(CUR)) * 8192 + 4096 + (tid + 256) * 8); \
    { u16x8 cl_, ch_;                                                           \
      _Pragma("unroll") for (int j_ = 0; j_ < 8; j_++) cl_[j_] = f2bf(rLo[j_]); \
      _Pragma("unroll") for (int j_ = 0; j_ < 8; j_++) ch_[j_] = f2bf(rHi[j_]); \
      *(u16x8*)(sA + (1-(CUR)) * 4096 + tid * 8) = cl_;                         \
      *(u16x8*)(sA + (1-(CUR)) * 4096 + 2048 + tid * 8) = ch_; }                \
    rLo = *(const f32x8*)(xrow + (((KT) + 128) & 1023));                        \
    rHi = *(const f32x8*)(xrow + (((KT) + 160) & 1023));                        \
    asm volatile("s_waitcnt lgkmcnt(0)" ::: "memory");                          \
    asm volatile("s_waitcnt vmcnt(6)" ::: "memory");                            \
    __builtin_amdgcn_s_barrier();                                               \
    { const u16* cA_ = sA + (CUR) * 4096; const u16* cB_ = sB + (CUR) * 8192;   \
      _Pragma("unroll") for (int h_ = 0; h_ < 2; h_++) {                        \
        bf16x8 af_[4], bv_[2];                                                  \
        _Pragma("unroll") for (int i_ = 0; i_ < 4; i_++)                        \
            af_[i_] = *(const bf16x8*)(cA_ + h_ * 2048 + aO + i_ * 512);        \
        _Pragma("unroll") for (int j_ = 0; j_ < 2; j_++)                        \
            bv_[j_] = *(const bf16x8*)(cB_ + h_ * 4096 + bO + j_ * 512);        \
        _Pragma("unroll") for (int i_ = 0; i_ < 4; i_++)                        \
        _Pragma("unroll") for (int j_ = 0; j_ < 2; j_++)                        \
            acc[i_][j_] = __builtin_amdgcn_mfma_f32_16x16x32_bf16(              \
                af_[i_], bv_[j_], acc[i_][j_], 0, 0, 0); } }                    \
} while (0)

__global__ __launch_bounds__(256) void kgemm_xp(
    const float* __restrict__ x, const u16* __restrict__ wpb,
    const float* __restrict__ bp, u16* __restrict__ xpb)
{
    __shared__ u16 sA[8192], sB[16384];          // BK=64: 2x4096 / 2x8192
    const int id = blockIdx.x;                   // 768 blocks
    const int cb = (id >> 3) & 3;                // col block 0..3
    const int yb = (id & 7) + ((id >> 5) << 3);  // row block 0..191
    const int rowBase = yb * 64, colBase = cb * 128;
    const int tid = threadIdx.x, l = tid & 63, wv = tid >> 6;
    const int m16 = l & 15, k8 = l >> 4;
    const int kc = (tid & 3) * 8;
    const float* xrow = x + (size_t)(rowBase + (tid >> 2)) * 1024 + kc;
    const u16* Bb = wpb + (size_t)colBase * 1024;
    const size_t rb0 = (size_t)(tid >> 2) * 1024 + kc;
    const size_t rb1 = rb0 + 64 * 1024;
    const int aO = m16 * 32 + k8 * 8;
    const int bO = (wv * 32 + m16) * 32 + k8 * 8;
    f32x4 acc[4][2];
#pragma unroll
    for (int i = 0; i < 4; i++)
#pragma unroll
        for (int j = 0; j < 2; j++) acc[i][j] = (f32x4){0.f,0.f,0.f,0.f};

    // prologue: tile0 (both halves) -> buf0; A(1) halves left in flight in rLo/rHi
    gload16(Bb + rb0,      sB + tid * 8);
    gload16(Bb + rb1,      sB + (tid + 256) * 8);
    gload16(Bb + rb0 + 32, sB + 4096 + tid * 8);
    gload16(Bb + rb1 + 32, sB + 4096 + (tid + 256) * 8);
    {
        f32x8 a0 = *(const f32x8*)(xrow);        // auto-wait drains B(0) too (once)
        f32x8 a1 = *(const f32x8*)(xrow + 32);
        u16x8 c0, c1;
#pragma unroll
        for (int j = 0; j < 8; j++) c0[j] = f2bf(a0[j]);
#pragma unroll
        for (int j = 0; j < 8; j++) c1[j] = f2bf(a1[j]);
        *(u16x8*)(sA + tid * 8) = c0;
        *(u16x8*)(sA + 2048 + tid * 8) = c1;
    }
    f32x8 rLo = *(const f32x8*)(xrow + 64);      // A(1) lo, consumed at t=0
    f32x8 rHi = *(const f32x8*)(xrow + 96);      // A(1) hi
    asm volatile("s_waitcnt lgkmcnt(0)" ::: "memory");

    for (int kt = 0; kt < 896; kt += 128) {      // t = 0..13 (pairs)
        XP_STEP64(kt, 0);
        XP_STEP64(kt + 64, 1);
    }
    XP_STEP64(896, 0);                           // t = 14, stages tile 15 -> buf1
    // t = 15 (cur = 1): nothing left to stage
    __builtin_amdgcn_s_barrier();
    asm volatile("s_waitcnt vmcnt(0) lgkmcnt(0)" ::: "memory");
    __builtin_amdgcn_s_barrier();
    {
        const u16* cA = sA + 4096;
        const u16* cB = sB + 8192;
#pragma unroll
        for (int h = 0; h < 2; h++) {
            bf16x8 af[4], bv[2];
#pragma unroll
            for (int i = 0; i < 4; i++) af[i] = *(const bf16x8*)(cA + h * 2048 + aO + i * 512);
#pragma unroll
            for (int j = 0; j < 2; j++) bv[j] = *(const bf16x8*)(cB + h * 4096 + bO + j * 512);
#pragma unroll
            for (int i = 0; i < 4; i++)
#pragma unroll
                for (int j = 0; j < 2; j++)
                    acc[i][j] = __builtin_amdgcn_mfma_f32_16x16x32_bf16(af[i], bv[j], acc[i][j], 0, 0, 0);
        }
    }
#pragma unroll
    for (int in = 0; in < 2; in++) {
        const int gc = colBase + wv * 32 + in * 16 + m16;
        const float bv = bp[gc];
#pragma unroll
        for (int im = 0; im < 4; im++) {
            const int gr = rowBase + im * 16 + k8 * 4;
#pragma unroll
            for (int r = 0; r < 4; r++)
                xpb[(size_t)(gr + r) * 512 + gc] = f2bf(acc[im][in][r] + bv);
        }
    }
}

// ---------------- G2: h1[t,k] = relu(xg @ W1^T + b1) -> bf16 ----------------
// 64x128 tiles on the verified mfma_loop64 (BK=64). 1D grid 2304 with XCD
// swizzle: within each seg (64 blocks), the 8 blocks on one XCD share one
// B col-tile (xb = i&3, yb-high = (i>>2)&1 fixed by i%8).
__global__ __launch_bounds__(256) void kgemm_h1(
    const u16* __restrict__ xpb, const u16* __restrict__ w1b,
    const float* __restrict__ opb1, u16* __restrict__ h1b)
{
    __shared__ u16 sA[8192], sB[16384];
    const int id = blockIdx.x;
    const int seg = id >> 6, i = id & 63, t = seg / 3;
    const int xb = i & 3;
    const int yb = (i >> 3) + ((i >> 2) & 1) * 8;   // [0,16)
    const int rowBase = yb * 64, colBase = xb * 128;
    f32x4 acc[4][2];
#pragma unroll
    for (int i1 = 0; i1 < 4; i1++)
#pragma unroll
        for (int j = 0; j < 2; j++) acc[i1][j] = (f32x4){0.f,0.f,0.f,0.f};
    // A row gi -> memory row gi*12 + t  (pitch 12*512)
    mfma_loop64(xpb + (size_t)rowBase * 6144 + (size_t)t * 512, 6144,
                w1b + (size_t)seg * 262144 + (size_t)colBase * 512, 512, 512, sA, sB, acc);
    const int tid = threadIdx.x, l = tid & 63, wv = tid >> 6;
    const int m16 = l & 15, k8 = l >> 4;
    u16* hseg = h1b + (size_t)seg * 524288;
#pragma unroll
    for (int in = 0; in < 2; in++) {
        const int gc = colBase + wv * 32 + in * 16 + m16;
        const float bv = opb1[seg * 512 + gc];
#pragma unroll
        for (int im = 0; im < 4; im++) {
            const int gr = rowBase + im * 16 + k8 * 4;
#pragma unroll
            for (int r = 0; r < 4; r++)
                hseg[(size_t)(gr + r) * 512 + gc] = f2bf(fmaxf(acc[im][in][r] + bv, 0.f));
        }
    }
}

// ------- G3: out[t] = sum_k w[t,k]*relu(h1 @ W2^T + b2) -> f32 + bf16 (verified R7) -------
__global__ __launch_bounds__(256) void kgemm_out(
    const u16* __restrict__ h1b, const u16* __restrict__ w2b,
    const float* __restrict__ opb2, const float* __restrict__ wbuf,
    float* __restrict__ outF, u16* __restrict__ outb)
{
    __shared__ u16 sA[8192], sB[16384];          // BK=64: 2x4096 / 2x8192
    const int id = blockIdx.x;
    const int t = id >> 6, i = id & 63;
    const int a = i & 1, b2i = (i >> 1) & 3, q = i >> 3;
    const int xb = 2 * a + (q & 1), yb = 4 * b2i + (q >> 1);
    const int rowBase = yb * 64, colBase = xb * 128;
    const int tid = threadIdx.x, l = tid & 63, wv = tid >> 6;
    const int m16 = l & 15, k8 = l >> 4;
    float oac[4][2][4];
#pragma unroll
    for (int i1 = 0; i1 < 4; i1++)
#pragma unroll
        for (int j = 0; j < 2; j++)
#pragma unroll
            for (int r = 0; r < 4; r++) oac[i1][j][r] = 0.f;

    for (int kk = 0; kk < 3; kk++) {
        const int seg = t * 3 + kk;
        f32x4 acc[4][2];
#pragma unroll
        for (int i1 = 0; i1 < 4; i1++)
#pragma unroll
            for (int j = 0; j < 2; j++) acc[i1][j] = (f32x4){0.f,0.f,0.f,0.f};
        mfma_loop64(h1b + ((size_t)seg * 1024 + rowBase) * 512, 512,
                    w2b + (size_t)seg * 262144 + (size_t)colBase * 512, 512, 512, sA, sB, acc);
        const float wk = wbuf[seg];
#pragma unroll
        for (int in = 0; in < 2; in++) {
            const float bv = opb2[seg * 512 + colBase + wv * 32 + in * 16 + m16];
#pragma unroll
            for (int im = 0; im < 4; im++)
#pragma unroll
                for (int r = 0; r < 4; r++)
                    oac[im][in][r] += wk * fmaxf(acc[im][in][r] + bv, 0.f);
        }
    }
#pragma unroll
    for (int im = 0; im < 4; im++)
#pragma unroll
        for (int r = 0; r < 4; r++) {
            const int gi = rowBase + im * 16 + k8 * 4 + r;
            const size_t b = (size_t)gi * 12 + t;   // scatter back to patch order
#pragma unroll
            for (int in = 0; in < 2; in++) {
                const int gc = colBase + wv * 32 + in * 16 + m16;
                const float v = oac[im][in][r];
                outF[b * 512 + gc] = v;
                outb[b * 512 + gc] = f2bf(v);
            }
        }
}

// ------- G4+G5 fused: pred = out @ phW^T + phb  |  rh = relu(out @ rW1^T + bias_rh) -------
// 64x128 tiles on the verified mfma_loop64 (BK=64). 1D grid 2304; each XCD
// runs all 12 bz for one A row-panel (A re-read 11x from L2).
__global__ __launch_bounds__(256) void kgemm_predrh(
    const u16* __restrict__ outb, const u16* __restrict__ phwb,
    const float* __restrict__ phb, const u16* __restrict__ rw1b,
    const float* __restrict__ bias_rh, float* __restrict__ outPred,
    u16* __restrict__ rhb)
{
    __shared__ u16 sA[8192], sB[16384];
    const int id = blockIdx.x;
    const int j = id >> 3;                        // [0,288)
    const int bz = j % 12;                        // 0..7 pred colblocks, 8..11 rh
    const int yb = (id & 7) + (j / 12) * 8;       // [0,192)
    const int rowBase = yb * 64;
    const bool isPred = bz < 8;
    const int colBase = (isPred ? bz : bz - 8) * 128;
    const u16* Bb = isPred ? (phwb + (size_t)colBase * 512)
                           : (rw1b + (size_t)colBase * 512);
    f32x4 acc[4][2];
#pragma unroll
    for (int i1 = 0; i1 < 4; i1++)
#pragma unroll
        for (int j1 = 0; j1 < 2; j1++) acc[i1][j1] = (f32x4){0.f,0.f,0.f,0.f};
    mfma_loop64(outb + (size_t)rowBase * 512, 512, Bb, 512, 512, sA, sB, acc);
    const int tid = threadIdx.x, l = tid & 63, wv = tid >> 6;
    const int m16 = l & 15, k8 = l >> 4;
    if (isPred) {
#pragma unroll
        for (int in = 0; in < 2; in++) {
            const int gc = colBase + wv * 32 + in * 16 + m16;
            const float bv = phb[gc];
#pragma unroll
            for (int im = 0; im < 4; im++) {
                const int gr = rowBase + im * 16 + k8 * 4;
#pragma unroll
                for (int r = 0; r < 4; r++)
                    outPred[(size_t)(gr + r) * 1024 + gc] = acc[im][in][r] + bv;
            }
        }
    } else {
#pragma unroll
        for (int in = 0; in < 2; in++) {
            const int gc = colBase + wv * 32 + in * 16 + m16;
#pragma unroll
            for (int im = 0; im < 4; im++) {
                const int gr = rowBase + im * 16 + k8 * 4;
#pragma unroll
                for (int r = 0; r < 4; r++) {
                    const int b = gr + r;
                    const float bv = bias_rh[(b % 12) * 512 + gc];
                    rhb[(size_t)b * 512 + gc] = f2bf(fmaxf(acc[im][in][r] + bv, 0.f));
                }
            }
        }
    }
}

// ---------------- per-group streaming reductions -> per-wave partials ----------------
// quarter-split: 4096 waves, each handles 3 of the 12 t-rows of one group.
__global__ __launch_bounds__(256) void rowred(
    const float* __restrict__ outF, const u16* __restrict__ xpb,
    const float* __restrict__ noise, float* __restrict__ partials)
{
    const int tid = threadIdx.x, l = tid & 63, wv = tid >> 6;
    const int gw = blockIdx.x * 4 + wv;          // 0..4095
    const int g = gw >> 2, q = gw & 3;
    const size_t base = (size_t)g * 12 * 512 + l * 8;
    float* pout = partials + (size_t)g * 60 + q * 15;
#pragma unroll
    for (int t0 = 0; t0 < 3; t0++) {
        const int t = q * 3 + t0;
        const size_t off = base + (size_t)t * 512;
        f32x8 ov = *(const f32x8*)(outF + off);
        f32x8 nv = *(const f32x8*)(noise + off);
        u16x8 xv = *(const u16x8*)(xpb + off);
        float s1 = 0, s2 = 0, s3 = 0, s4 = 0;
#pragma unroll
        for (int j = 0; j < 8; j++) {
            float xg = bf2f(xv[j]);
            float o = ov[j];
            float d = o - xg;
            s1 += d * d; s2 += xg * xg; s3 += fabsf(o); s4 += nv[j] * nv[j];
        }
#pragma unroll
        for (int off2 = 32; off2 > 0; off2 >>= 1) {
            s1 += __shfl_xor(s1, off2);
            s2 += __shfl_xor(s2, off2);
            s3 += __shfl_xor(s3, off2);
            s4 += __shfl_xor(s4, off2);
        }
        if (l < 5) {
            float v = (l == 0) ? s1 : (l == 1) ? s2 : (l == 2) ? s3
                    : (l == 3) ? s4 : s1 * s1;
            pout[t0 * 5 + l] = v;
        }
    }
}

// ---------------- partial-reduce + signals -> decision + folded routing bias ----------------
__global__ __launch_bounds__(256) void sig_kernel(
    const float* __restrict__ op_logits, const float* __restrict__ id_emb,
    const float* __restrict__ rW1, const float* __restrict__ rb1,
    const float* __restrict__ gW1, const float* __restrict__ gb1,
    const float* __restrict__ gW2, const float* __restrict__ gb2,
    const float* __restrict__ partials, float* __restrict__ bias_rh,
    float* __restrict__ outDec)
{
    const int t = blockIdx.x, tid = threadIdx.x;
    __shared__ float sig[7], ex7[7], gch[512], red[256], accv[5];
    float a[5] = {0.f, 0.f, 0.f, 0.f, 0.f};
    for (int g = tid; g < 1024; g += 256) {
        const float* p = partials + (size_t)g * 60 + t * 5;
#pragma unroll
        for (int s = 0; s < 5; s++) a[s] += p[s];
    }
#pragma unroll
    for (int s = 0; s < 5; s++) {
        red[tid] = a[s]; __syncthreads();
        for (int k = 128; k > 0; k >>= 1) { if (tid < k) red[tid] += red[tid + k]; __syncthreads(); }
        if (tid == 0) accv[s] = red[0];
        __syncthreads();
    }
    if (tid == 0) {
        float l0 = op_logits[t*3+0], l1 = op_logits[t*3+1], l2 = op_logits[t*3+2];
        float mx = fmaxf(l0, fmaxf(l1, l2));
        float e0 = expf(l0-mx), e1 = expf(l1-mx), e2 = expf(l2-mx);
        float es = e0 + e1 + e2;
        float w0 = e0/es, w1 = e1/es, w2 = e2/es;
        float mean = (w0 + w1 + w2) * (1.f/3.f);
        float var = ((w0-mean)*(w0-mean) + (w1-mean)*(w1-mean) + (w2-mean)*(w2-mean)) * 0.5f;
        float conflict = sqrtf(var);
        float inv_s = 1.f / (w0 + w1 + w2 + 1e-6f);
        float u0 = w0*inv_s, u1 = w1*inv_s, u2 = w2*inv_s;
        float ent = -(u0*logf(fmaxf(u0,1e-6f)) + u1*logf(fmaxf(u1,1e-6f)) + u2*logf(fmaxf(u2,1e-6f)));
        const float inv = 1.f / (1024.f * 512.f);
        float plast = accv[0] * inv;                 // pred_err mean == last_plasticity
        float nov   = accv[1] * inv;
        float spars = accv[2] * inv;
        float plasticity = 1e-4f * accv[3] * inv;
        float pe2 = accv[4] * (1.f / (1024.f * 512.f * 512.f));
        float na = 0.01f * plast;
        float rvar = pe2 - 2.f*na*plast + na*na;
        sig[0]=plasticity; sig[1]=nov; sig[2]=plast; sig[3]=ent; sig[4]=spars; sig[5]=-plast; sig[6]=rvar;
        ex7[0]=id_emb[t*4+0]; ex7[1]=id_emb[t*4+1]; ex7[2]=id_emb[t*4+2]; ex7[3]=id_emb[t*4+3];
        ex7[4]=nov; ex7[5]=conflict; ex7[6]=plast;
    }
    __syncthreads();
    for (int h = tid; h < 512; h += 256) {
        float aa = gb1[t*512 + h];
#pragma unroll
        for (int j = 0; j < 7; j++) aa += gW1[(t*512 + h)*7 + j] * sig[j];
        gch[h] = fmaxf(aa, 0.f);
        float bb = rb1[h];
#pragma unroll
        for (int e = 0; e < 7; e++) bb += ex7[e] * rW1[(size_t)h * 519 + 512 + e];
        bias_rh[t*512 + h] = bb;
    }
    __syncthreads();
    float p0 = 0.f, p1 = 0.f;
    for (int h = tid; h < 512; h += 256) {
        p0 += gW2[(t*2 + 0)*512 + h] * gch[h];
        p1 += gW2[(t*2 + 1)*512 + h] * gch[h];
    }
    red[tid] = p0; __syncthreads();
    for (int s = 128; s > 0; s >>= 1) { if (tid < s) red[tid] += red[tid + s]; __syncthreads(); }
    if (tid == 0) outDec[t*2 + 0] = red[0] + gb2[t*2 + 0];
    __syncthreads();
    red[tid] = p1; __syncthreads();
    for (int s = 128; s > 0; s >>= 1) { if (tid < s) red[tid] += red[tid + s]; __syncthreads(); }
    if (tid == 0) outDec[t*2 + 1] = red[0] + gb2[t*2 + 1];
}

// ---------------- logits = rh @ rW2^T + rb2 (one wave per row) ----------------
__global__ __launch_bounds__(256) void logits_kernel(
    const u16* __restrict__ rhb, const float* __restrict__ rW2,
    const float* __restrict__ rb2, float* __restrict__ outLg)
{
    __shared__ float T2[512 * 13];
    __shared__ float rb2s[16];
    const int tid = threadIdx.x;
    for (int i = tid; i < 6656; i += 256) {
        int o = i >> 9, j = i & 511;
        T2[j * 13 + o] = rW2[i];    // transposed+13-pitch: conflict-free reads
    }
    if (tid < 13) rb2s[tid] = rb2[tid];
    __syncthreads();
    const int l = tid & 63, wv = tid >> 6;
    const size_t b = (size_t)blockIdx.x * 4 + wv;
    const u16* rrow = rhb + b * 512;
    float rv[8];
#pragma unroll
    for (int jj = 0; jj < 8; jj++) rv[jj] = bf2f(rrow[l + 64 * jj]);
    float p[13];
#pragma unroll
    for (int o = 0; o < 13; o++) p[o] = 0.f;
#pragma unroll
    for (int jj = 0; jj < 8; jj++) {
        const float* tp = T2 + (l + 64 * jj) * 13;
#pragma unroll
        for (int o = 0; o < 13; o++) p[o] += rv[jj] * tp[o];
    }
#pragma unroll
    for (int o = 0; o < 13; o++) {
#pragma unroll
        for (int off = 32; off > 0; off >>= 1) p[o] += __shfl_xor(p[o], off);
    }
    if (l == 0) {
        float* orow = outLg + b * 13;
#pragma unroll
        for (int o = 0; o < 13; o++) orow[o] = p[o] + rb2s[o];
    }
}

extern "C" void kernel_launch(void* const* d_in, const int* in_sizes, int n_in,
                              void* d_out, int out_size, void* d_ws, size_t ws_size,
                              hipStream_t stream)
{
    const float* x         = (const float*)d_in[0];
    const float* Wp        = (const float*)d_in[1];
    const float* bp        = (const float*)d_in[2];
    const float* opW1      = (const float*)d_in[3];
    const float* opb1      = (const float*)d_in[4];
    const float* opW2      = (const float*)d_in[5];
    const float* opb2      = (const float*)d_in[6];
    const float* op_logits = (const float*)d_in[7];
    const float* id_emb    = (const float*)d_in[8];
    const float* rW1       = (const float*)d_in[9];
    const float* rb1       = (const float*)d_in[10];
    const float* rW2       = (const float*)d_in[11];
    const float* rb2       = (const float*)d_in[12];
    const float* gW1       = (const float*)d_in[13];
    const float* gb1       = (const float*)d_in[14];
    const float* gW2       = (const float*)d_in[15];
    const float* gb2       = (const float*)d_in[16];
    const float* phW       = (const float*)d_in[17];
    const float* phb       = (const float*)d_in[18];
    const float* noise     = (const float*)d_in[19];

    char* ws = (char*)d_ws;
    float* wbuf    = (float*)(ws + WS_W);
    float* bias_rh = (float*)(ws + WS_BIASRH);
    u16* wpb  = (u16*)(ws + WS_WPB);
    u16* phwb = (u16*)(ws + WS_PHWB);
    u16* rw1b = (u16*)(ws + WS_RW1B);
    u16* w1b  = (u16*)(ws + WS_W1B);
    u16* w2b  = (u16*)(ws + WS_W2B);
    u16* xpb  = (u16*)(ws + WS_XPB);
    u16* h1b  = (u16*)(ws + WS_H1B);
    u16* outb = (u16*)(ws + WS_OUTB);
    u16* rhb  = (u16*)(ws + WS_RHB);
    float* partials = (float*)(ws + WS_W1B);   // aliases w1b, dead after kgemm_h1

    float* outF    = (float*)d_out;
    float* outLg   = outF + OUT_LG;
    float* outPred = outF + OUT_PRED;
    float* outDec  = outF + OUT_DEC;

    // 20185088 f32 elems / 2048 per block = 9856 blocks (exact)
    cvt6<<<9856, 256, 0, stream>>>(opW1, w1b, opW2, w2b, Wp, wpb,
                                   phW, phwb, rW1, rw1b, op_logits, wbuf);
    kgemm_xp  <<<768,  256, 0, stream>>>(x, wpb, bp, xpb);
    kgemm_h1  <<<2304, 256, 0, stream>>>(xpb, w1b, opb1, h1b);
    kgemm_out <<<768,  256, 0, stream>>>(h1b, w2b, opb2, wbuf, outF, outb);
    rowred    <<<1024, 256, 0, stream>>>(outF, xpb, noise, partials);
    sig_kernel<<<12,   256, 0, stream>>>(op_logits, id_emb, rW1, rb1, gW1, gb1,
                                         gW2, gb2, partials, bias_rh, outDec);
    kgemm_predrh<<<2304, 256, 0, stream>>>(outb, phwb, phb, rw1b, bias_rh,
                                           outPred, rhb);
    logits_kernel<<<3072, 256, 0, stream>>>(rhb, rW2, rb2, outLg);
}